// Round 9
// baseline (1090.757 us; speedup 1.0000x reference)
//
#include <hip/hip_runtime.h>
#include <hip/hip_fp16.h>

#define NN 50000
#define EE 800000
#define LL 6
constexpr float EPSF = 1e-5f;

typedef _Float16 f16x8 __attribute__((ext_vector_type(8)));
typedef _Float16 f16x2 __attribute__((ext_vector_type(2)));
typedef float f32x4 __attribute__((ext_vector_type(4)));
typedef unsigned short u16x8 __attribute__((ext_vector_type(8)));

__device__ __forceinline__ float leaky(float v, float s) { return v > 0.f ? v : s * v; }

__device__ __forceinline__ f16x2 asf2(unsigned int u) {
    union { unsigned int u; f16x2 f; } x; x.u = u; return x.f;
}
__device__ __forceinline__ unsigned int asu2(f16x2 f) {
    union { f16x2 f; unsigned int u; } x; x.f = f; return x.u;
}
__device__ __forceinline__ f16x2 lrelu2_02(f16x2 v) {
    return __builtin_elementwise_max(v, v * (_Float16)0.2f);
}
__device__ __forceinline__ f16x2 pk2(float a, float b) {
    f16x2 r; r[0] = (_Float16)a; r[1] = (_Float16)b; return r;
}
// fp32 -> one fp8 e4m3 byte
__device__ __forceinline__ unsigned char f2fp8(float v) {
    return (unsigned char)(__builtin_amdgcn_cvt_pk_fp8_f32(v, v, 0, false) & 0xff);
}

// async global->LDS, 16B per lane
#define GLD16(gp, sp) __builtin_amdgcn_global_load_lds( \
    (const __attribute__((address_space(1))) unsigned int*)(uintptr_t)(gp), \
    (__attribute__((address_space(3))) unsigned int*)(uintptr_t)(sp), 16, 0, 0)

// ------------- fused prep: all transposes + biasfold + att cvt + softmax -------------
__global__ __launch_bounds__(256) void prep_k(
    const float* __restrict__ win_w, const float* __restrict__ Wl,
    const float* __restrict__ Wr, const float* __restrict__ h1_w,
    const float* __restrict__ h2_w, const float* __restrict__ ln_g,
    const float* __restrict__ ln_b, const float* __restrict__ bl,
    const float* __restrict__ br, const float* __restrict__ att,
    const float* __restrict__ sw,
    __half* __restrict__ winT, __half* __restrict__ WlrT,
    __half* __restrict__ h1T, __half* __restrict__ h2T,
    __half* __restrict__ att_h, float* __restrict__ biasLR, float* __restrict__ wsm)
{
    __shared__ float t[64][65];
    const int bid = blockIdx.x, tid = threadIdx.x;
    if (bid < 224) {
        const float* in; __half* out; const float* gamma = nullptr;
        int K, N, kb, nb;
        if (bid < 8)        { in = win_w; out = winT; K = 128; N = 256; kb = bid >> 2; nb = bid & 3; }
        else if (bid < 104) { int i = bid - 8; int l = i >> 4, r = i & 15;
            in = Wl + (size_t)l * 65536; out = WlrT + (size_t)l * 131072;
            gamma = ln_g + l * 256; K = 256; N = 256; kb = r >> 2; nb = r & 3; }
        else if (bid < 200) { int i = bid - 104; int l = i >> 4, r = i & 15;
            in = Wr + (size_t)l * 65536; out = WlrT + (size_t)l * 131072 + 65536;
            gamma = ln_g + l * 256; K = 256; N = 256; kb = r >> 2; nb = r & 3; }
        else if (bid < 216) { int i = bid - 200; in = h1_w; out = h1T; K = 256; N = 256; kb = i >> 2; nb = i & 3; }
        else                { int i = bid - 216; in = h2_w; out = h2T; K = 256; N = 128; kb = i >> 1; nb = i & 1; }
        const int k0 = kb * 64, n0 = nb * 64;
        {
            int kl = tid >> 2, np = (tid & 3) * 16;
            const float* ip = in + (size_t)(k0 + kl) * N + n0 + np;
            float4 a = *(const float4*)(ip + 0);
            float4 b = *(const float4*)(ip + 4);
            float4 c = *(const float4*)(ip + 8);
            float4 d = *(const float4*)(ip + 12);
            t[kl][np + 0] = a.x; t[kl][np + 1] = a.y; t[kl][np + 2] = a.z; t[kl][np + 3] = a.w;
            t[kl][np + 4] = b.x; t[kl][np + 5] = b.y; t[kl][np + 6] = b.z; t[kl][np + 7] = b.w;
            t[kl][np + 8] = c.x; t[kl][np + 9] = c.y; t[kl][np +10] = c.z; t[kl][np +11] = c.w;
            t[kl][np +12] = d.x; t[kl][np +13] = d.y; t[kl][np +14] = d.z; t[kl][np +15] = d.w;
        }
        __syncthreads();
        {
            int nl = tid >> 2, kp = (tid & 3) * 16;
            u16x8 o0, o1;
#pragma unroll
            for (int i = 0; i < 8; ++i) {
                float g0 = gamma ? gamma[k0 + kp + i] : 1.f;
                float g1 = gamma ? gamma[k0 + kp + 8 + i] : 1.f;
                o0[i] = __half_as_ushort(__float2half(t[kp + i][nl] * g0));
                o1[i] = __half_as_ushort(__float2half(t[kp + 8 + i][nl] * g1));
            }
            unsigned short* op = (unsigned short*)out + (size_t)(n0 + nl) * K + k0 + kp;
            *(u16x8*)(op + 0) = o0;
            *(u16x8*)(op + 8) = o1;
        }
    } else if (bid < 236) {
        int i = bid - 224, l = i >> 1, side = i & 1, n = tid;
        const float* W = side ? Wr : Wl;
        const float* b = side ? br : bl;
        const float* lb = ln_b + l * 256;
        const float* Wp = W + (size_t)l * 65536;
        float acc = b[l * 256 + n];
        for (int k = 0; k < 256; ++k) acc = fmaf(lb[k], Wp[(size_t)k * 256 + n], acc);
        biasLR[l * 512 + side * 256 + n] = acc;
    } else if (bid < 242) {
        int l = bid - 236;
        att_h[l * 256 + tid] = __float2half(att[l * 256 + tid]);
    } else if (tid == 0) {
        float m = -1e30f;
        for (int l = 0; l < LL; ++l) m = fmaxf(m, sw[l]);
        float e[LL]; float s = 0.f;
        for (int l = 0; l < LL; ++l) { e[l] = __expf(sw[l] - m); s += e[l]; }
        float w[LL];
        for (int l = 0; l < LL; ++l) { w[l] = e[l] / s; wsm[l] = w[l]; }
        for (int l = 0; l < LL; ++l) {
            float S = 0.f;
            for (int k = l; k < LL; ++k) S += w[k];
            wsm[8 + l] = S;   // suffix sums
        }
    }
}

// ------- generic fp32 -> fp16 -------
__global__ __launch_bounds__(256) void cvt_h_k(const float* __restrict__ in,
                                               __half* __restrict__ out, int n)
{
    int i = blockIdx.x * 256 + threadIdx.x;
    if (i < n) out[i] = __float2half(in[i]);
}

// ---- fp16 MFMA GEMM, 128x256 tile, BK=64, global_load_lds, XOR swizzle ----
// Each block covers ALL 256 cols of its column-panel (bn = blockIdx.y*256).
// Wave grid 2x2: each wave 64 rows x 128 cols (acc 4x8).
// Output: if C8 != null and blockIdx.y==0 -> fp8 bytes at C8[row*256+cc];
// else fp16 at C16[row*256+cc]. ACT 1: bn+leaky. ACT 0: bias only.
template<int ACT>
__global__ __launch_bounds__(256) void gemm256_k(
    const __half* __restrict__ A, const __half* __restrict__ Bt,
    const float* __restrict__ bias, const float* __restrict__ g2,
    const float* __restrict__ b2,
    unsigned char* __restrict__ C8, __half* __restrict__ C16,
    int M, int K)
{
    __shared__ _Float16 As[128 * 64];
    __shared__ _Float16 Bs[256 * 64];
    const int tid = threadIdx.x, lane = tid & 63, wave = tid >> 6;
    const int bm = blockIdx.x * 128, bn = blockIdx.y * 256;
    const int wm = (wave & 1) * 64, wn = (wave >> 1) * 128;
    const int mrow = lane & 15;
    const int sg = lane >> 3;
    const int sc = (lane & 7) ^ sg;
    const __half* BtB = Bt + (size_t)bn * K;

    f32x4 acc[4][8];
#pragma unroll
    for (int i = 0; i < 4; ++i)
#pragma unroll
        for (int j = 0; j < 8; ++j) acc[i][j] = (f32x4){0.f, 0.f, 0.f, 0.f};

    for (int k0 = 0; k0 < K; k0 += 64) {
#pragma unroll
        for (int t = 0; t < 4; ++t) {
            int R = 32 * wave + 8 * t;
            int ar = bm + R + sg; if (ar >= M) ar = M - 1;
            GLD16(A + (size_t)ar * K + k0 + sc * 8, &As[R * 64]);
        }
#pragma unroll
        for (int t = 0; t < 8; ++t) {
            int R = 64 * wave + 8 * t;
            GLD16(BtB + (size_t)(R + sg) * K + k0 + sc * 8, &Bs[R * 64]);
        }
        __syncthreads();
#pragma unroll
        for (int s2 = 0; s2 < 2; ++s2) {
            const int c = s2 * 4 + (lane >> 4);
            f16x8 af[4], bf[8];
#pragma unroll
            for (int i = 0; i < 4; ++i) {
                int r = wm + 16 * i + mrow;
                af[i] = *(const f16x8*)&As[r * 64 + ((c ^ (r & 7)) * 8)];
            }
#pragma unroll
            for (int j = 0; j < 8; ++j) {
                int r = wn + 16 * j + mrow;
                bf[j] = *(const f16x8*)&Bs[r * 64 + ((c ^ (r & 7)) * 8)];
            }
#pragma unroll
            for (int i = 0; i < 4; ++i)
#pragma unroll
                for (int j = 0; j < 8; ++j)
                    acc[i][j] = __builtin_amdgcn_mfma_f32_16x16x32_f16(af[i], bf[j], acc[i][j], 0, 0, 0);
        }
        __syncthreads();
    }

    const float inv_s = 0.9999950000374997f; // 1/sqrt(1+1e-5)
    const int rq = (lane >> 4) * 4;
    const bool do8 = (C8 != nullptr) && (blockIdx.y == 0);
    float bsj[8], gj[8], bbj[8];
#pragma unroll
    for (int j = 0; j < 8; ++j) {
        int cc = bn + wn + 16 * j + mrow;
        bsj[j] = bias[cc];
        if constexpr (ACT == 1) { gj[j] = g2[cc]; bbj[j] = b2[cc]; }
    }
#pragma unroll
    for (int i = 0; i < 4; ++i)
#pragma unroll
        for (int r = 0; r < 4; ++r) {
            int grow = bm + wm + 16 * i + rq + r;
            if (grow >= M) continue;
#pragma unroll
            for (int j = 0; j < 8; ++j) {
                int cc = wn + 16 * j + mrow;   // 0..255 within panel
                float v = acc[i][j][r] + bsj[j];
                if constexpr (ACT == 1) v = leaky(v * inv_s * gj[j] + bbj[j], 0.1f);
                if (do8) C8[(size_t)grow * 256 + cc] = f2fp8(v);
                else     C16[(size_t)grow * 256 + cc] = __float2half(v);
            }
        }
}

// ------- fp16 MFMA GEMM, 128x128 tile (exit-2, N=128) -------
__global__ __launch_bounds__(256) void gemm128_k(
    const __half* __restrict__ A, const __half* __restrict__ Bt,
    const float* __restrict__ bias, __half* __restrict__ C,
    int M, int K, int N)
{
    __shared__ _Float16 As[128 * 64];
    __shared__ _Float16 Bs[128 * 64];
    const int tid = threadIdx.x, lane = tid & 63, wave = tid >> 6;
    const int bm = blockIdx.x * 128, bn = 0;
    const int wm = (wave & 1) * 64, wn = (wave >> 1) * 64;
    const int mrow = lane & 15;
    const int sg = lane >> 3;
    const int sc = (lane & 7) ^ sg;

    f32x4 acc[4][4];
#pragma unroll
    for (int i = 0; i < 4; ++i)
#pragma unroll
        for (int j = 0; j < 4; ++j) acc[i][j] = (f32x4){0.f, 0.f, 0.f, 0.f};

    for (int k0 = 0; k0 < K; k0 += 64) {
#pragma unroll
        for (int t = 0; t < 4; ++t) {
            int R = 32 * wave + 8 * t;
            int ar = bm + R + sg; if (ar >= M) ar = M - 1;
            GLD16(A + (size_t)ar * K + k0 + sc * 8, &As[R * 64]);
        }
#pragma unroll
        for (int t = 0; t < 4; ++t) {
            int R = 32 * wave + 8 * t;
            GLD16(Bt + (size_t)(bn + R + sg) * K + k0 + sc * 8, &Bs[R * 64]);
        }
        __syncthreads();
#pragma unroll
        for (int s2 = 0; s2 < 2; ++s2) {
            const int c = s2 * 4 + (lane >> 4);
            f16x8 af[4], bf[4];
#pragma unroll
            for (int i = 0; i < 4; ++i) {
                int r = wm + 16 * i + mrow;
                af[i] = *(const f16x8*)&As[r * 64 + ((c ^ (r & 7)) * 8)];
            }
#pragma unroll
            for (int j = 0; j < 4; ++j) {
                int r = wn + 16 * j + mrow;
                bf[j] = *(const f16x8*)&Bs[r * 64 + ((c ^ (r & 7)) * 8)];
            }
#pragma unroll
            for (int i = 0; i < 4; ++i)
#pragma unroll
                for (int j = 0; j < 4; ++j)
                    acc[i][j] = __builtin_amdgcn_mfma_f32_16x16x32_f16(af[i], bf[j], acc[i][j], 0, 0, 0);
        }
        __syncthreads();
    }

    const int rq = (lane >> 4) * 4;
    float bsj[4];
#pragma unroll
    for (int j = 0; j < 4; ++j) bsj[j] = bias[bn + wn + 16 * j + mrow];
#pragma unroll
    for (int i = 0; i < 4; ++i)
#pragma unroll
        for (int r = 0; r < 4; ++r) {
            int grow = bm + wm + 16 * i + rq + r;
            if (grow >= M) continue;
#pragma unroll
            for (int j = 0; j < 4; ++j) {
                int cc = bn + wn + 16 * j + mrow;
                float v = leaky(acc[i][j][r] + bsj[j], 0.1f);
                C[(size_t)grow * N + cc] = __float2half(v);
            }
        }
}

// ------- entry LN: norm = (h16 - mu)*rsig -> fp16; hacc init = h16 -------
__global__ __launch_bounds__(256) void ln_norm_k(const __half* __restrict__ h16,
                                                 __half* __restrict__ hacc,
                                                 __half* __restrict__ normed, int N)
{
    int wv = blockIdx.x * 4 + (threadIdx.x >> 6);
    if (wv >= N) return;
    int lane = threadIdx.x & 63;
    size_t off = (size_t)wv * 256 + lane * 4;
    uint2 u = *(const uint2*)((const unsigned short*)h16 + off);
    f16x2 p0 = asf2(u.x), p1 = asf2(u.y);
    float v0 = (float)p0[0], v1 = (float)p0[1], v2 = (float)p1[0], v3 = (float)p1[1];
    float s = v0 + v1 + v2 + v3;
#pragma unroll
    for (int o = 1; o < 64; o <<= 1) s += __shfl_xor(s, o);
    float m = s * (1.f / 256.f);
    float d0 = v0 - m, d1 = v1 - m, d2 = v2 - m, d3 = v3 - m;
    float q = d0 * d0 + d1 * d1 + d2 * d2 + d3 * d3;
#pragma unroll
    for (int o = 1; o < 64; o <<= 1) q += __shfl_xor(q, o);
    float rs = rsqrtf(q * (1.f / 256.f) + EPSF);
    *(uint2*)((unsigned short*)hacc + off) = u;
    uint2 o2;
    o2.x = asu2(pk2(d0 * rs, d1 * rs));
    o2.y = asu2(pk2(d2 * rs, d3 * rs));
    *(uint2*)((unsigned short*)normed + off) = o2;
}

// ---------------- CSR build ----------------
__global__ __launch_bounds__(256) void hist_k(const int* __restrict__ ei, int E, int N,
                                              int* __restrict__ counts)
{
    int e = blockIdx.x * 256 + threadIdx.x;
    int Etot = E + N;
    if (e >= Etot) return;
    int d = (e < E) ? ei[E + e] : (e - E);
    atomicAdd(&counts[d], 1);
}

// ---- 3-phase grid scan ----
__global__ __launch_bounds__(256) void scanA_k(const int* __restrict__ counts,
                                               int* __restrict__ bsum, int N)
{
    int i = blockIdx.x * 256 + threadIdx.x;
    int v = (i < N) ? counts[i] : 0;
    int s = v;
#pragma unroll
    for (int o = 1; o < 64; o <<= 1) s += __shfl_xor(s, o);
    __shared__ int ws[4];
    if ((threadIdx.x & 63) == 0) ws[threadIdx.x >> 6] = s;
    __syncthreads();
    if (threadIdx.x == 0) bsum[blockIdx.x] = ws[0] + ws[1] + ws[2] + ws[3];
}

__global__ __launch_bounds__(256) void scanB_k(const int* __restrict__ bsum,
                                               int* __restrict__ bpre, int nb)
{
    int t = threadIdx.x;
    int v = (t < nb) ? bsum[t] : 0;
    int lane = t & 63, w = t >> 6;
    int incl = v;
#pragma unroll
    for (int o = 1; o < 64; o <<= 1) { int u = __shfl_up(incl, o); if (lane >= o) incl += u; }
    __shared__ int ws[4];
    if (lane == 63) ws[w] = incl;
    __syncthreads();
    if (t == 0) { int run = 0; for (int k = 0; k < 4; ++k) { int x = ws[k]; ws[k] = run; run += x; } }
    __syncthreads();
    if (t < nb) bpre[t] = ws[w] + incl - v;
}

__global__ __launch_bounds__(256) void scanC_k(int* __restrict__ counts,
                                               const int* __restrict__ bpre,
                                               int* __restrict__ offsets, int N, int Etot)
{
    int i = blockIdx.x * 256 + threadIdx.x;
    int v = (i < N) ? counts[i] : 0;
    int lane = threadIdx.x & 63, w = threadIdx.x >> 6;
    int incl = v;
#pragma unroll
    for (int o = 1; o < 64; o <<= 1) { int u = __shfl_up(incl, o); if (lane >= o) incl += u; }
    __shared__ int ws[4];
    if (lane == 63) ws[w] = incl;
    __syncthreads();
    if (threadIdx.x == 0) { int run = 0; for (int k = 0; k < 4; ++k) { int x = ws[k]; ws[k] = run; run += x; } }
    __syncthreads();
    int ex = bpre[blockIdx.x] + ws[w] + incl - v;
    if (i < N) { offsets[i] = ex; counts[i] = ex; }   // counts becomes the scatter cursor
    if (i == 0) offsets[N] = Etot;
}

__global__ __launch_bounds__(256) void scatter_k(const int* __restrict__ ei, int E, int N,
                                                 int* __restrict__ cursor, int* __restrict__ eidx)
{
    int e = blockIdx.x * 256 + threadIdx.x;
    int Etot = E + N;
    if (e >= Etot) return;
    int s, d;
    if (e < E) { s = ei[e]; d = ei[E + e]; }
    else       { s = e - E; d = s; }
    int pos = atomicAdd(&cursor[d], 1);
    eidx[pos] = s;
}

// ------- Edge aggregation: wave/node, 4 slots x 16 lanes x 16 ch; fp8 xl gather -------
__global__ __launch_bounds__(256) void edge_k(
    const unsigned char* __restrict__ xl8, const __half* __restrict__ xr16,
    const __half* __restrict__ atth, const float* __restrict__ convb,
    const int* __restrict__ offsets, const int* __restrict__ eidx,
    __half* __restrict__ h16, __half* __restrict__ hacc,
    __half* __restrict__ normed,
    const float* __restrict__ wsm, const float* __restrict__ scales,
    int layer, int N)
{
    int wv = blockIdx.x * 4 + (threadIdx.x >> 6);
    if (wv >= N) return;
    const int lane = threadIdx.x & 63;
    const int slot = lane >> 4, sl = lane & 15;
    const int c0 = sl * 16;               // this lane's 16-channel segment (head = sl>>1)

    f16x2 atv[8], xrv[8];
    {
        const unsigned short* ap = (const unsigned short*)atth + c0;
        const unsigned short* xp = (const unsigned short*)xr16 + (size_t)wv * 256 + c0;
        uint4 a0 = *(const uint4*)ap, a1 = *(const uint4*)(ap + 8);
        uint4 x0 = *(const uint4*)xp, x1 = *(const uint4*)(xp + 8);
        atv[0]=asf2(a0.x); atv[1]=asf2(a0.y); atv[2]=asf2(a0.z); atv[3]=asf2(a0.w);
        atv[4]=asf2(a1.x); atv[5]=asf2(a1.y); atv[6]=asf2(a1.z); atv[7]=asf2(a1.w);
        xrv[0]=asf2(x0.x); xrv[1]=asf2(x0.y); xrv[2]=asf2(x0.z); xrv[3]=asf2(x0.w);
        xrv[4]=asf2(x1.x); xrv[5]=asf2(x1.y); xrv[6]=asf2(x1.z); xrv[7]=asf2(x1.w);
    }
    const int e0 = offsets[wv], e1 = offsets[wv + 1], e1m = e1 - 1;
    f16x2 a2[8];
#pragma unroll
    for (int p = 0; p < 8; ++p) a2[p] = pk2(0.f, 0.f);
    float den = 0.f;

    for (int base = e0; base < e1; base += 4) {
        int e = base + slot;
        bool v = e < e1;
        int s = eidx[v ? e : e1m];
        uint4 w = *(const uint4*)(xl8 + (size_t)s * 256 + c0);   // 16 fp8 ch
        f16x2 xv[8];
        xv[0] = __builtin_amdgcn_cvt_scalef32_pk_f16_fp8(w.x, 1.0f, false);
        xv[1] = __builtin_amdgcn_cvt_scalef32_pk_f16_fp8(w.x, 1.0f, true);
        xv[2] = __builtin_amdgcn_cvt_scalef32_pk_f16_fp8(w.y, 1.0f, false);
        xv[3] = __builtin_amdgcn_cvt_scalef32_pk_f16_fp8(w.y, 1.0f, true);
        xv[4] = __builtin_amdgcn_cvt_scalef32_pk_f16_fp8(w.z, 1.0f, false);
        xv[5] = __builtin_amdgcn_cvt_scalef32_pk_f16_fp8(w.z, 1.0f, true);
        xv[6] = __builtin_amdgcn_cvt_scalef32_pk_f16_fp8(w.w, 1.0f, false);
        xv[7] = __builtin_amdgcn_cvt_scalef32_pk_f16_fp8(w.w, 1.0f, true);
        float pm = 0.f;
#pragma unroll
        for (int p = 0; p < 8; ++p) {
            f16x2 t = lrelu2_02(xv[p] + xrv[p]);
            pm = __builtin_amdgcn_fdot2(t, atv[p], pm, false);
        }
        pm += __shfl_xor(pm, 1);             // head = 2 lanes (32 ch)
        float exf = v ? __expf(pm) : 0.f;
        den += exf;
        _Float16 eh = (_Float16)exf;
        f16x2 e2; e2[0] = eh; e2[1] = eh;
#pragma unroll
        for (int p = 0; p < 8; ++p) a2[p] += xv[p] * e2;
    }

    // combine across the 4 slots (lane bits 4,5)
    den += __shfl_xor(den, 16); den += __shfl_xor(den, 32);
#pragma unroll
    for (int p = 0; p < 8; ++p) {
        a2[p] += asf2((unsigned int)__shfl_xor((int)asu2(a2[p]), 16));
        a2[p] += asf2((unsigned int)__shfl_xor((int)asu2(a2[p]), 32));
    }

    // all-lane epilogue: lane handles 4 channels cc = c0 + 4*slot (a2[2*slot], a2[2*slot+1])
    const int p0 = 2 * slot;
    const float inv = 1.f / den;
    const float sc = scales[layer], Sl = wsm[8 + layer];
    const int cc = c0 + 4 * slot;
    const size_t rb = (size_t)wv * 256 + cc;
    float4 cb = *(const float4*)(convb + cc);
    uint2 hu = *(const uint2*)((const unsigned short*)h16 + rb);
    f16x2 h0 = asf2(hu.x), h1 = asf2(hu.y);
    float d00 = sc * leaky(fmaf((float)a2[p0][0],     inv, cb.x), 0.1f);
    float d01 = sc * leaky(fmaf((float)a2[p0][1],     inv, cb.y), 0.1f);
    float d10 = sc * leaky(fmaf((float)a2[p0 + 1][0], inv, cb.z), 0.1f);
    float d11 = sc * leaky(fmaf((float)a2[p0 + 1][1], inv, cb.w), 0.1f);
    float hn0 = (float)h0[0] + d00, hn1 = (float)h0[1] + d01;
    float hn2 = (float)h1[0] + d10, hn3 = (float)h1[1] + d11;

    // hacc += S_l * d   (hsum = h_entry + sum_l S_l d_l; softmax weights sum to 1)
    {
        uint2 au = *(const uint2*)((const unsigned short*)hacc + rb);
        f16x2 A0 = asf2(au.x), A1 = asf2(au.y);
        uint2 ao;
        ao.x = asu2(pk2(fmaf(Sl, d00, (float)A0[0]), fmaf(Sl, d01, (float)A0[1])));
        ao.y = asu2(pk2(fmaf(Sl, d10, (float)A1[0]), fmaf(Sl, d11, (float)A1[1])));
        *(uint2*)((unsigned short*)hacc + rb) = ao;
    }

    if (layer != LL - 1) {
        uint2 ho;
        ho.x = asu2(pk2(hn0, hn1));
        ho.y = asu2(pk2(hn2, hn3));
        *(uint2*)((unsigned short*)h16 + rb) = ho;
        // LN stats across the full wave (each lane holds 4 distinct channels)
        float s1 = hn0 + hn1 + hn2 + hn3;
#pragma unroll
        for (int o = 1; o < 64; o <<= 1) s1 += __shfl_xor(s1, o);
        float m = s1 * (1.f / 256.f);
        float dd0 = hn0 - m, dd1 = hn1 - m, dd2 = hn2 - m, dd3 = hn3 - m;
        float qv = dd0 * dd0 + dd1 * dd1 + dd2 * dd2 + dd3 * dd3;
#pragma unroll
        for (int o = 1; o < 64; o <<= 1) qv += __shfl_xor(qv, o);
        float rs = rsqrtf(qv * (1.f / 256.f) + EPSF);
        uint2 no;
        no.x = asu2(pk2(dd0 * rs, dd1 * rs));
        no.y = asu2(pk2(dd2 * rs, dd3 * rs));
        *(uint2*)((unsigned short*)normed + rb) = no;
    }
}

// ---------------- final y2h[N,128] @ h3_w[128,1] + h3_b ----------------
__global__ __launch_bounds__(256) void out_k(const __half* __restrict__ y2,
                                             const float* __restrict__ w,
                                             const float* __restrict__ b,
                                             float* __restrict__ out, int N)
{
    int wv = blockIdx.x * 4 + (threadIdx.x >> 6);
    if (wv >= N) return;
    int lane = threadIdx.x & 63;
    unsigned int u = *(const unsigned int*)((const unsigned short*)y2 + (size_t)wv * 128 + lane * 2);
    f16x2 v = asf2(u);
    float2 ww = *(const float2*)(w + lane * 2);
    float pm = (float)v[0] * ww.x + (float)v[1] * ww.y;
#pragma unroll
    for (int off = 1; off < 64; off <<= 1) pm += __shfl_xor(pm, off);
    if (lane == 0) out[wv] = pm + b[0];
}

extern "C" void kernel_launch(void* const* d_in, const int* in_sizes, int n_in,
                              void* d_out, int out_size, void* d_ws, size_t ws_size,
                              hipStream_t stream)
{
    const int N = NN, E = EE, Etot = EE + NN;
    const float* x      = (const float*)d_in[0];
    const int*   ei     = (const int*)  d_in[1];
    const float* win_w  = (const float*)d_in[2];
    const float* win_b  = (const float*)d_in[3];
    const float* bn1_g  = (const float*)d_in[4];
    const float* bn1_b  = (const float*)d_in[5];
    const float* ln_g   = (const float*)d_in[6];
    const float* ln_b   = (const float*)d_in[7];
    const float* Wl     = (const float*)d_in[8];
    const float* bl     = (const float*)d_in[9];
    const float* Wr     = (const float*)d_in[10];
    const float* br     = (const float*)d_in[11];
    const float* att    = (const float*)d_in[12];
    const float* conv_b = (const float*)d_in[13];
    const float* scales = (const float*)d_in[14];
    const float* sw     = (const float*)d_in[15];
    const float* h1_w   = (const float*)d_in[16];
    const float* h1_b   = (const float*)d_in[17];
    const float* bn2_g  = (const float*)d_in[18];
    const float* bn2_b  = (const float*)d_in[19];
    const float* h2_w   = (const float*)d_in[20];
    const float* h2_b   = (const float*)d_in[21];
    const float* h3_w   = (const float*)d_in[22];
    const float* h3_b   = (const float*)d_in[23];

    char* p = (char*)d_ws;
    auto take = [&](size_t b) -> char* {
        char* q = p; p += (b + 255) & ~(size_t)255; return q;
    };
    __half* h16     = (__half*)take((size_t)N * 256 * 2);
    __half* hacc    = (__half*)take((size_t)N * 256 * 2);
    __half* norm    = (__half*)take((size_t)N * 256 * 2);
    unsigned char* xl8 = (unsigned char*)take((size_t)N * 256);
    __half* xr16    = (__half*)take((size_t)N * 256 * 2);
    __half* xh      = (__half*)take((size_t)N * 128 * 2);
    __half* y2h     = (__half*)take((size_t)N * 128 * 2);
    float* wsm      = (float*)take(256);
    int*   offsets  = (int*)take((size_t)(N + 1) * 4);
    int*   cursor   = (int*)take((size_t)N * 4);
    int*   eidx     = (int*)take((size_t)Etot * 4);
    int*   bsum     = (int*)take(256 * 4);
    int*   bpre     = (int*)take(256 * 4);
    __half* winT    = (__half*)take((size_t)256 * 128 * 2);
    __half* WlrT    = (__half*)take((size_t)LL * 512 * 256 * 2);
    __half* h1T     = (__half*)take((size_t)256 * 256 * 2);
    __half* h2T     = (__half*)take((size_t)128 * 256 * 2);
    __half* att_h   = (__half*)take((size_t)LL * 256 * 2);
    float* biasLR   = (float*)take((size_t)LL * 512 * 4);
    __half* y1b = xr16;   // xr16 dead after layer-5 edge_k

    const int EB = (Etot + 255) / 256;
    const int NB = (N + 3) / 4;
    const int SB = (N + 255) / 256;    // 196 scan blocks
    const int MB = (N + 127) / 128;    // 391 gemm row blocks

    // CSR build (cursor doubles as counts, then as scatter cursor after scanC)
    hipMemsetAsync(cursor, 0, (size_t)N * 4, stream);
    hist_k<<<EB, 256, 0, stream>>>(ei, E, N, cursor);
    scanA_k<<<SB, 256, 0, stream>>>(cursor, bsum, N);
    scanB_k<<<1, 256, 0, stream>>>(bsum, bpre, SB);
    scanC_k<<<SB, 256, 0, stream>>>(cursor, bpre, offsets, N, Etot);
    scatter_k<<<EB, 256, 0, stream>>>(ei, E, N, cursor, eidx);

    // fused prep: transposes(+gamma fold), biasfold(+beta fold), att cvt, softmax+suffix
    prep_k<<<243, 256, 0, stream>>>(win_w, Wl, Wr, h1_w, h2_w, ln_g, ln_b, bl, br, att, sw,
                                    winT, WlrT, h1T, h2T, att_h, biasLR, wsm);
    cvt_h_k<<<(N * 128 + 255) / 256, 256, 0, stream>>>(x, xh, N * 128);

    // entry: h16 = leaky(bn1(x @ win_w + win_b), 0.1) fp16; norm + hacc init
    gemm256_k<1><<<dim3(MB, 1), 256, 0, stream>>>(xh, winT, win_b, bn1_g, bn1_b,
                                                  nullptr, h16, N, 128);
    ln_norm_k<<<NB, 256, 0, stream>>>(h16, hacc, norm, N);

    for (int l = 0; l < LL; ++l) {
        gemm256_k<0><<<dim3(MB, 2), 256, 0, stream>>>(norm, WlrT + (size_t)l * 131072,
                                                      biasLR + l * 512, nullptr, nullptr,
                                                      xl8, xr16, N, 256);
        edge_k<<<NB, 256, 0, stream>>>(xl8, xr16, att_h + l * 256, conv_b + l * 256,
                                       offsets, eidx, h16, hacc, norm,
                                       wsm, scales, l, N);
    }

    // exit MLP on hacc (= softmax-weighted layer sum, fp16)
    gemm256_k<1><<<dim3(MB, 1), 256, 0, stream>>>(hacc, h1T, h1_b, bn2_g, bn2_b,
                                                  nullptr, y1b, N, 256);
    gemm128_k<<<dim3(MB, 1), 256, 0, stream>>>(y1b, h2T, h2_b, y2h, N, 256, 128);
    out_k<<<NB, 256, 0, stream>>>(y2h, h3_w, h3_b, (float*)d_out, N);
}

// Round 11
// 963.312 us; speedup vs baseline: 1.1323x; 1.1323x over previous
//
#include <hip/hip_runtime.h>
#include <hip/hip_fp16.h>

#define NN 50000
#define EE 800000
#define LL 6
constexpr float EPSF = 1e-5f;

typedef _Float16 f16x8 __attribute__((ext_vector_type(8)));
typedef _Float16 f16x2 __attribute__((ext_vector_type(2)));
typedef float f32x4 __attribute__((ext_vector_type(4)));
typedef unsigned short u16x8 __attribute__((ext_vector_type(8)));

__device__ __forceinline__ float leaky(float v, float s) { return v > 0.f ? v : s * v; }

__device__ __forceinline__ f16x2 asf2(unsigned int u) {
    union { unsigned int u; f16x2 f; } x; x.u = u; return x.f;
}
__device__ __forceinline__ unsigned int asu2(f16x2 f) {
    union { f16x2 f; unsigned int u; } x; x.f = f; return x.u;
}
__device__ __forceinline__ f16x2 lrelu2_02(f16x2 v) {
    return __builtin_elementwise_max(v, v * (_Float16)0.2f);
}
__device__ __forceinline__ f16x2 pk2(float a, float b) {
    f16x2 r; r[0] = (_Float16)a; r[1] = (_Float16)b; return r;
}
// fp32 -> one fp8 e4m3 byte
__device__ __forceinline__ unsigned char f2fp8(float v) {
    return (unsigned char)(__builtin_amdgcn_cvt_pk_fp8_f32(v, v, 0, false) & 0xff);
}

// async global->LDS, 16B per lane
#define GLD16(gp, sp) __builtin_amdgcn_global_load_lds( \
    (const __attribute__((address_space(1))) unsigned int*)(uintptr_t)(gp), \
    (__attribute__((address_space(3))) unsigned int*)(uintptr_t)(sp), 16, 0, 0)

// ------------- fused prep: all transposes + biasfold + att cvt + softmax -------------
__global__ __launch_bounds__(256) void prep_k(
    const float* __restrict__ win_w, const float* __restrict__ Wl,
    const float* __restrict__ Wr, const float* __restrict__ h1_w,
    const float* __restrict__ h2_w, const float* __restrict__ ln_g,
    const float* __restrict__ ln_b, const float* __restrict__ bl,
    const float* __restrict__ br, const float* __restrict__ att,
    const float* __restrict__ sw,
    __half* __restrict__ winT, __half* __restrict__ WlrT,
    __half* __restrict__ h1T, __half* __restrict__ h2T,
    __half* __restrict__ att_h, float* __restrict__ biasLR, float* __restrict__ wsm)
{
    __shared__ float t[64][65];
    const int bid = blockIdx.x, tid = threadIdx.x;
    if (bid < 224) {
        const float* in; __half* out; const float* gamma = nullptr;
        int K, N, kb, nb;
        if (bid < 8)        { in = win_w; out = winT; K = 128; N = 256; kb = bid >> 2; nb = bid & 3; }
        else if (bid < 104) { int i = bid - 8; int l = i >> 4, r = i & 15;
            in = Wl + (size_t)l * 65536; out = WlrT + (size_t)l * 131072;
            gamma = ln_g + l * 256; K = 256; N = 256; kb = r >> 2; nb = r & 3; }
        else if (bid < 200) { int i = bid - 104; int l = i >> 4, r = i & 15;
            in = Wr + (size_t)l * 65536; out = WlrT + (size_t)l * 131072 + 65536;
            gamma = ln_g + l * 256; K = 256; N = 256; kb = r >> 2; nb = r & 3; }
        else if (bid < 216) { int i = bid - 200; in = h1_w; out = h1T; K = 256; N = 256; kb = i >> 2; nb = i & 3; }
        else                { int i = bid - 216; in = h2_w; out = h2T; K = 256; N = 128; kb = i >> 1; nb = i & 1; }
        const int k0 = kb * 64, n0 = nb * 64;
        {
            int kl = tid >> 2, np = (tid & 3) * 16;
            const float* ip = in + (size_t)(k0 + kl) * N + n0 + np;
            float4 a = *(const float4*)(ip + 0);
            float4 b = *(const float4*)(ip + 4);
            float4 c = *(const float4*)(ip + 8);
            float4 d = *(const float4*)(ip + 12);
            t[kl][np + 0] = a.x; t[kl][np + 1] = a.y; t[kl][np + 2] = a.z; t[kl][np + 3] = a.w;
            t[kl][np + 4] = b.x; t[kl][np + 5] = b.y; t[kl][np + 6] = b.z; t[kl][np + 7] = b.w;
            t[kl][np + 8] = c.x; t[kl][np + 9] = c.y; t[kl][np +10] = c.z; t[kl][np +11] = c.w;
            t[kl][np +12] = d.x; t[kl][np +13] = d.y; t[kl][np +14] = d.z; t[kl][np +15] = d.w;
        }
        __syncthreads();
        {
            int nl = tid >> 2, kp = (tid & 3) * 16;
            u16x8 o0, o1;
#pragma unroll
            for (int i = 0; i < 8; ++i) {
                float g0 = gamma ? gamma[k0 + kp + i] : 1.f;
                float g1 = gamma ? gamma[k0 + kp + 8 + i] : 1.f;
                o0[i] = __half_as_ushort(__float2half(t[kp + i][nl] * g0));
                o1[i] = __half_as_ushort(__float2half(t[kp + 8 + i][nl] * g1));
            }
            unsigned short* op = (unsigned short*)out + (size_t)(n0 + nl) * K + k0 + kp;
            *(u16x8*)(op + 0) = o0;
            *(u16x8*)(op + 8) = o1;
        }
    } else if (bid < 236) {
        int i = bid - 224, l = i >> 1, side = i & 1, n = tid;
        const float* W = side ? Wr : Wl;
        const float* b = side ? br : bl;
        const float* lb = ln_b + l * 256;
        const float* Wp = W + (size_t)l * 65536;
        float acc = b[l * 256 + n];
        for (int k = 0; k < 256; ++k) acc = fmaf(lb[k], Wp[(size_t)k * 256 + n], acc);
        biasLR[l * 512 + side * 256 + n] = acc;
    } else if (bid < 242) {
        int l = bid - 236;
        att_h[l * 256 + tid] = __float2half(att[l * 256 + tid]);
    } else if (tid == 0) {
        float m = -1e30f;
        for (int l = 0; l < LL; ++l) m = fmaxf(m, sw[l]);
        float e[LL]; float s = 0.f;
        for (int l = 0; l < LL; ++l) { e[l] = __expf(sw[l] - m); s += e[l]; }
        float w[LL];
        for (int l = 0; l < LL; ++l) { w[l] = e[l] / s; wsm[l] = w[l]; }
        for (int l = 0; l < LL; ++l) {
            float S = 0.f;
            for (int k = l; k < LL; ++k) S += w[k];
            wsm[8 + l] = S;   // suffix sums
        }
    }
}

// ------- generic fp32 -> fp16 -------
__global__ __launch_bounds__(256) void cvt_h_k(const float* __restrict__ in,
                                               __half* __restrict__ out, int n)
{
    int i = blockIdx.x * 256 + threadIdx.x;
    if (i < n) out[i] = __float2half(in[i]);
}

// ------- fp16 MFMA GEMM, 128x128 tile, BK=64, global_load_lds staging, XOR swizzle ----
// OUT: 0 = fp32 Cv, 1 = fp16 Cv, 2 = split (cols<256 -> fp8 C8, cols>=256 -> fp16 C16)
template<int ACT, int OUT>
__global__ __launch_bounds__(256) void gemm_h_k(
    const __half* __restrict__ A, const __half* __restrict__ Bt,
    const float* __restrict__ bias, const float* __restrict__ g2,
    const float* __restrict__ b2, void* __restrict__ Cv,
    unsigned char* __restrict__ C8, __half* __restrict__ C16,
    int M, int K, int N)
{
    __shared__ _Float16 As[128 * 64];
    __shared__ _Float16 Bs[128 * 64];
    const int tid = threadIdx.x, lane = tid & 63, wave = tid >> 6;
    const int bm = blockIdx.x * 128, bn = blockIdx.y * 128;
    const int wm = (wave & 1) * 64, wn = (wave >> 1) * 64;
    const int mrow = lane & 15;
    const int sg = lane >> 3;
    const int sc = (lane & 7) ^ sg;

    f32x4 acc[4][4];
#pragma unroll
    for (int i = 0; i < 4; ++i)
#pragma unroll
        for (int j = 0; j < 4; ++j) acc[i][j] = (f32x4){0.f, 0.f, 0.f, 0.f};

    for (int k0 = 0; k0 < K; k0 += 64) {
#pragma unroll
        for (int t = 0; t < 4; ++t) {
            int R = 32 * wave + 8 * t;
            int ar = bm + R + sg; if (ar >= M) ar = M - 1;
            GLD16(A + (size_t)ar * K + k0 + sc * 8, &As[R * 64]);
        }
#pragma unroll
        for (int t = 0; t < 4; ++t) {
            int R = 32 * wave + 8 * t;
            GLD16(Bt + (size_t)(bn + R + sg) * K + k0 + sc * 8, &Bs[R * 64]);
        }
        __syncthreads();
#pragma unroll
        for (int s2 = 0; s2 < 2; ++s2) {
            const int c = s2 * 4 + (lane >> 4);
            f16x8 af[4], bf[4];
#pragma unroll
            for (int i = 0; i < 4; ++i) {
                int r = wm + 16 * i + mrow;
                af[i] = *(const f16x8*)&As[r * 64 + ((c ^ (r & 7)) * 8)];
            }
#pragma unroll
            for (int j = 0; j < 4; ++j) {
                int r = wn + 16 * j + mrow;
                bf[j] = *(const f16x8*)&Bs[r * 64 + ((c ^ (r & 7)) * 8)];
            }
#pragma unroll
            for (int i = 0; i < 4; ++i)
#pragma unroll
                for (int j = 0; j < 4; ++j)
                    acc[i][j] = __builtin_amdgcn_mfma_f32_16x16x32_f16(af[i], bf[j], acc[i][j], 0, 0, 0);
        }
        __syncthreads();
    }

    const float inv_s = 0.9999950000374997f; // 1/sqrt(1+1e-5)
    const int rq = (lane >> 4) * 4;
    float bsj[4], gj[4], bbj[4];
#pragma unroll
    for (int j = 0; j < 4; ++j) {
        int cc = bn + wn + 16 * j + mrow;
        bsj[j] = bias[cc];
        if constexpr (ACT == 1) { gj[j] = g2[cc]; bbj[j] = b2[cc]; }
    }
#pragma unroll
    for (int i = 0; i < 4; ++i)
#pragma unroll
        for (int r = 0; r < 4; ++r) {
            int grow = bm + wm + 16 * i + rq + r;
            if (grow >= M) continue;
#pragma unroll
            for (int j = 0; j < 4; ++j) {
                int cc = bn + wn + 16 * j + mrow;
                float v = acc[i][j][r] + bsj[j];
                if constexpr (ACT == 1) v = leaky(v * inv_s * gj[j] + bbj[j], 0.1f);
                else if constexpr (ACT == 2) v = leaky(v, 0.1f);
                if constexpr (OUT == 0)      ((float*)Cv)[(size_t)grow * N + cc] = v;
                else if constexpr (OUT == 1) ((__half*)Cv)[(size_t)grow * N + cc] = __float2half(v);
                else {
                    if (bn < 256) C8[(size_t)grow * 256 + cc] = f2fp8(v);
                    else          C16[(size_t)grow * 256 + (cc - 256)] = __float2half(v);
                }
            }
        }
}

// ------- entry LN: norm = (h16 - mu)*rsig -> fp16; hacc init = h16 -------
__global__ __launch_bounds__(256) void ln_norm_k(const __half* __restrict__ h16,
                                                 __half* __restrict__ hacc,
                                                 __half* __restrict__ normed, int N)
{
    int wv = blockIdx.x * 4 + (threadIdx.x >> 6);
    if (wv >= N) return;
    int lane = threadIdx.x & 63;
    size_t off = (size_t)wv * 256 + lane * 4;
    uint2 u = *(const uint2*)((const unsigned short*)h16 + off);
    f16x2 p0 = asf2(u.x), p1 = asf2(u.y);
    float v0 = (float)p0[0], v1 = (float)p0[1], v2 = (float)p1[0], v3 = (float)p1[1];
    float s = v0 + v1 + v2 + v3;
#pragma unroll
    for (int o = 1; o < 64; o <<= 1) s += __shfl_xor(s, o);
    float m = s * (1.f / 256.f);
    float d0 = v0 - m, d1 = v1 - m, d2 = v2 - m, d3 = v3 - m;
    float q = d0 * d0 + d1 * d1 + d2 * d2 + d3 * d3;
#pragma unroll
    for (int o = 1; o < 64; o <<= 1) q += __shfl_xor(q, o);
    float rs = rsqrtf(q * (1.f / 256.f) + EPSF);
    *(uint2*)((unsigned short*)hacc + off) = u;
    uint2 o2;
    o2.x = asu2(pk2(d0 * rs, d1 * rs));
    o2.y = asu2(pk2(d2 * rs, d3 * rs));
    *(uint2*)((unsigned short*)normed + off) = o2;
}

// ---------------- CSR build ----------------
__global__ __launch_bounds__(256) void hist_k(const int* __restrict__ ei, int E, int N,
                                              int* __restrict__ counts)
{
    int e = blockIdx.x * 256 + threadIdx.x;
    int Etot = E + N;
    if (e >= Etot) return;
    int d = (e < E) ? ei[E + e] : (e - E);
    atomicAdd(&counts[d], 1);
}

// ---- 3-phase grid scan ----
__global__ __launch_bounds__(256) void scanA_k(const int* __restrict__ counts,
                                               int* __restrict__ bsum, int N)
{
    int i = blockIdx.x * 256 + threadIdx.x;
    int v = (i < N) ? counts[i] : 0;
    int s = v;
#pragma unroll
    for (int o = 1; o < 64; o <<= 1) s += __shfl_xor(s, o);
    __shared__ int ws[4];
    if ((threadIdx.x & 63) == 0) ws[threadIdx.x >> 6] = s;
    __syncthreads();
    if (threadIdx.x == 0) bsum[blockIdx.x] = ws[0] + ws[1] + ws[2] + ws[3];
}

__global__ __launch_bounds__(256) void scanB_k(const int* __restrict__ bsum,
                                               int* __restrict__ bpre, int nb)
{
    int t = threadIdx.x;
    int v = (t < nb) ? bsum[t] : 0;
    int lane = t & 63, w = t >> 6;
    int incl = v;
#pragma unroll
    for (int o = 1; o < 64; o <<= 1) { int u = __shfl_up(incl, o); if (lane >= o) incl += u; }
    __shared__ int ws[4];
    if (lane == 63) ws[w] = incl;
    __syncthreads();
    if (t == 0) { int run = 0; for (int k = 0; k < 4; ++k) { int x = ws[k]; ws[k] = run; run += x; } }
    __syncthreads();
    if (t < nb) bpre[t] = ws[w] + incl - v;
}

__global__ __launch_bounds__(256) void scanC_k(int* __restrict__ counts,
                                               const int* __restrict__ bpre,
                                               int* __restrict__ offsets, int N, int Etot)
{
    int i = blockIdx.x * 256 + threadIdx.x;
    int v = (i < N) ? counts[i] : 0;
    int lane = threadIdx.x & 63, w = threadIdx.x >> 6;
    int incl = v;
#pragma unroll
    for (int o = 1; o < 64; o <<= 1) { int u = __shfl_up(incl, o); if (lane >= o) incl += u; }
    __shared__ int ws[4];
    if (lane == 63) ws[w] = incl;
    __syncthreads();
    if (threadIdx.x == 0) { int run = 0; for (int k = 0; k < 4; ++k) { int x = ws[k]; ws[k] = run; run += x; } }
    __syncthreads();
    int ex = bpre[blockIdx.x] + ws[w] + incl - v;
    if (i < N) { offsets[i] = ex; counts[i] = ex; }   // counts becomes the scatter cursor
    if (i == 0) offsets[N] = Etot;
}

__global__ __launch_bounds__(256) void scatter_k(const int* __restrict__ ei, int E, int N,
                                                 int* __restrict__ cursor, int* __restrict__ eidx)
{
    int e = blockIdx.x * 256 + threadIdx.x;
    int Etot = E + N;
    if (e >= Etot) return;
    int s, d;
    if (e < E) { s = ei[e]; d = ei[E + e]; }
    else       { s = e - E; d = s; }
    int pos = atomicAdd(&cursor[d], 1);
    eidx[pos] = s;
}

// ------- Edge aggregation: wave/node, 4 slots x 16 lanes x 16 ch; fp8 xl gather -------
__global__ __launch_bounds__(256) void edge_k(
    const unsigned char* __restrict__ xl8, const __half* __restrict__ xr16,
    const __half* __restrict__ atth, const float* __restrict__ convb,
    const int* __restrict__ offsets, const int* __restrict__ eidx,
    __half* __restrict__ h16, __half* __restrict__ hacc,
    __half* __restrict__ normed,
    const float* __restrict__ wsm, const float* __restrict__ scales,
    int layer, int N)
{
    int wv = blockIdx.x * 4 + (threadIdx.x >> 6);
    if (wv >= N) return;
    const int lane = threadIdx.x & 63;
    const int slot = lane >> 4, sl = lane & 15;
    const int c0 = sl * 16;               // this lane's 16-channel segment (head = sl>>1)

    f16x2 atv[8], xrv[8];
    {
        const unsigned short* ap = (const unsigned short*)atth + c0;
        const unsigned short* xp = (const unsigned short*)xr16 + (size_t)wv * 256 + c0;
        uint4 a0 = *(const uint4*)ap, a1 = *(const uint4*)(ap + 8);
        uint4 x0 = *(const uint4*)xp, x1 = *(const uint4*)(xp + 8);
        atv[0]=asf2(a0.x); atv[1]=asf2(a0.y); atv[2]=asf2(a0.z); atv[3]=asf2(a0.w);
        atv[4]=asf2(a1.x); atv[5]=asf2(a1.y); atv[6]=asf2(a1.z); atv[7]=asf2(a1.w);
        xrv[0]=asf2(x0.x); xrv[1]=asf2(x0.y); xrv[2]=asf2(x0.z); xrv[3]=asf2(x0.w);
        xrv[4]=asf2(x1.x); xrv[5]=asf2(x1.y); xrv[6]=asf2(x1.z); xrv[7]=asf2(x1.w);
    }
    const int e0 = offsets[wv], e1 = offsets[wv + 1], e1m = e1 - 1;
    f16x2 a2[8];
#pragma unroll
    for (int p = 0; p < 8; ++p) a2[p] = pk2(0.f, 0.f);
    float den = 0.f;

    for (int base = e0; base < e1; base += 4) {
        int e = base + slot;
        bool v = e < e1;
        int s = eidx[v ? e : e1m];
        uint4 w = *(const uint4*)(xl8 + (size_t)s * 256 + c0);   // 16 fp8 ch
        f16x2 xv[8];
        xv[0] = __builtin_amdgcn_cvt_scalef32_pk_f16_fp8(w.x, 1.0f, false);
        xv[1] = __builtin_amdgcn_cvt_scalef32_pk_f16_fp8(w.x, 1.0f, true);
        xv[2] = __builtin_amdgcn_cvt_scalef32_pk_f16_fp8(w.y, 1.0f, false);
        xv[3] = __builtin_amdgcn_cvt_scalef32_pk_f16_fp8(w.y, 1.0f, true);
        xv[4] = __builtin_amdgcn_cvt_scalef32_pk_f16_fp8(w.z, 1.0f, false);
        xv[5] = __builtin_amdgcn_cvt_scalef32_pk_f16_fp8(w.z, 1.0f, true);
        xv[6] = __builtin_amdgcn_cvt_scalef32_pk_f16_fp8(w.w, 1.0f, false);
        xv[7] = __builtin_amdgcn_cvt_scalef32_pk_f16_fp8(w.w, 1.0f, true);
        float pm = 0.f;
#pragma unroll
        for (int p = 0; p < 8; ++p) {
            f16x2 t = lrelu2_02(xv[p] + xrv[p]);
            pm = __builtin_amdgcn_fdot2(t, atv[p], pm, false);
        }
        pm += __shfl_xor(pm, 1);             // head = 2 lanes (32 ch)
        float exf = v ? __expf(pm) : 0.f;
        den += exf;
        _Float16 eh = (_Float16)exf;
        f16x2 e2; e2[0] = eh; e2[1] = eh;
#pragma unroll
        for (int p = 0; p < 8; ++p) a2[p] += xv[p] * e2;
    }

    // combine across the 4 slots (lane bits 4,5)
    den += __shfl_xor(den, 16); den += __shfl_xor(den, 32);
#pragma unroll
    for (int p = 0; p < 8; ++p) {
        a2[p] += asf2((unsigned int)__shfl_xor((int)asu2(a2[p]), 16));
        a2[p] += asf2((unsigned int)__shfl_xor((int)asu2(a2[p]), 32));
    }

    // all-lane epilogue: lane handles 4 channels cc = c0 + 4*slot (a2[2*slot], a2[2*slot+1])
    const int p0 = 2 * slot;
    const float inv = 1.f / den;
    const float sc = scales[layer], Sl = wsm[8 + layer];
    const int cc = c0 + 4 * slot;
    const size_t rb = (size_t)wv * 256 + cc;
    float4 cb = *(const float4*)(convb + cc);
    uint2 hu = *(const uint2*)((const unsigned short*)h16 + rb);
    f16x2 h0 = asf2(hu.x), h1 = asf2(hu.y);
    float d00 = sc * leaky(fmaf((float)a2[p0][0],     inv, cb.x), 0.1f);
    float d01 = sc * leaky(fmaf((float)a2[p0][1],     inv, cb.y), 0.1f);
    float d10 = sc * leaky(fmaf((float)a2[p0 + 1][0], inv, cb.z), 0.1f);
    float d11 = sc * leaky(fmaf((float)a2[p0 + 1][1], inv, cb.w), 0.1f);
    float hn0 = (float)h0[0] + d00, hn1 = (float)h0[1] + d01;
    float hn2 = (float)h1[0] + d10, hn3 = (float)h1[1] + d11;

    // hacc += S_l * d   (hsum = h_entry + sum_l S_l d_l; softmax weights sum to 1)
    {
        uint2 au = *(const uint2*)((const unsigned short*)hacc + rb);
        f16x2 A0 = asf2(au.x), A1 = asf2(au.y);
        uint2 ao;
        ao.x = asu2(pk2(fmaf(Sl, d00, (float)A0[0]), fmaf(Sl, d01, (float)A0[1])));
        ao.y = asu2(pk2(fmaf(Sl, d10, (float)A1[0]), fmaf(Sl, d11, (float)A1[1])));
        *(uint2*)((unsigned short*)hacc + rb) = ao;
    }

    if (layer != LL - 1) {
        uint2 ho;
        ho.x = asu2(pk2(hn0, hn1));
        ho.y = asu2(pk2(hn2, hn3));
        *(uint2*)((unsigned short*)h16 + rb) = ho;
        // LN stats across the full wave (each lane holds 4 distinct channels)
        float s1 = hn0 + hn1 + hn2 + hn3;
#pragma unroll
        for (int o = 1; o < 64; o <<= 1) s1 += __shfl_xor(s1, o);
        float m = s1 * (1.f / 256.f);
        float dd0 = hn0 - m, dd1 = hn1 - m, dd2 = hn2 - m, dd3 = hn3 - m;
        float qv = dd0 * dd0 + dd1 * dd1 + dd2 * dd2 + dd3 * dd3;
#pragma unroll
        for (int o = 1; o < 64; o <<= 1) qv += __shfl_xor(qv, o);
        float rs = rsqrtf(qv * (1.f / 256.f) + EPSF);
        uint2 no;
        no.x = asu2(pk2(dd0 * rs, dd1 * rs));
        no.y = asu2(pk2(dd2 * rs, dd3 * rs));
        *(uint2*)((unsigned short*)normed + rb) = no;
    }
}

// ---------------- final y2[N,128] @ h3_w[128,1] + h3_b ----------------
__global__ __launch_bounds__(256) void out_k(const float* __restrict__ y2,
                                             const float* __restrict__ w,
                                             const float* __restrict__ b,
                                             float* __restrict__ out, int N)
{
    int wv = blockIdx.x * 4 + (threadIdx.x >> 6);
    if (wv >= N) return;
    int lane = threadIdx.x & 63;
    float2 v = *(const float2*)(y2 + (size_t)wv * 128 + lane * 2);
    float2 ww = *(const float2*)(w + lane * 2);
    float pm = v.x * ww.x + v.y * ww.y;
#pragma unroll
    for (int off = 1; off < 64; off <<= 1) pm += __shfl_xor(pm, off);
    if (lane == 0) out[wv] = pm + b[0];
}

extern "C" void kernel_launch(void* const* d_in, const int* in_sizes, int n_in,
                              void* d_out, int out_size, void* d_ws, size_t ws_size,
                              hipStream_t stream)
{
    const int N = NN, E = EE, Etot = EE + NN;
    const float* x      = (const float*)d_in[0];
    const int*   ei     = (const int*)  d_in[1];
    const float* win_w  = (const float*)d_in[2];
    const float* win_b  = (const float*)d_in[3];
    const float* bn1_g  = (const float*)d_in[4];
    const float* bn1_b  = (const float*)d_in[5];
    const float* ln_g   = (const float*)d_in[6];
    const float* ln_b   = (const float*)d_in[7];
    const float* Wl     = (const float*)d_in[8];
    const float* bl     = (const float*)d_in[9];
    const float* Wr     = (const float*)d_in[10];
    const float* br     = (const float*)d_in[11];
    const float* att    = (const float*)d_in[12];
    const float* conv_b = (const float*)d_in[13];
    const float* scales = (const float*)d_in[14];
    const float* sw     = (const float*)d_in[15];
    const float* h1_w   = (const float*)d_in[16];
    const float* h1_b   = (const float*)d_in[17];
    const float* bn2_g  = (const float*)d_in[18];
    const float* bn2_b  = (const float*)d_in[19];
    const float* h2_w   = (const float*)d_in[20];
    const float* h2_b   = (const float*)d_in[21];
    const float* h3_w   = (const float*)d_in[22];
    const float* h3_b   = (const float*)d_in[23];

    char* p = (char*)d_ws;
    auto take = [&](size_t b) -> char* {
        char* q = p; p += (b + 255) & ~(size_t)255; return q;
    };
    __half* h16     = (__half*)take((size_t)N * 256 * 2);
    __half* hacc    = (__half*)take((size_t)N * 256 * 2);
    __half* norm    = (__half*)take((size_t)N * 256 * 2);
    unsigned char* xl8 = (unsigned char*)take((size_t)N * 256);
    __half* xr16    = (__half*)take((size_t)N * 256 * 2);
    __half* xh      = (__half*)take((size_t)N * 128 * 2);
    float*  y2      = (float*)take((size_t)N * 128 * 4);
    float* wsm      = (float*)take(256);
    int*   offsets  = (int*)take((size_t)(N + 1) * 4);
    int*   cursor   = (int*)take((size_t)N * 4);
    int*   eidx     = (int*)take((size_t)Etot * 4);
    int*   bsum     = (int*)take(256 * 4);
    int*   bpre     = (int*)take(256 * 4);
    __half* winT    = (__half*)take((size_t)256 * 128 * 2);
    __half* WlrT    = (__half*)take((size_t)LL * 512 * 256 * 2);
    __half* h1T     = (__half*)take((size_t)256 * 256 * 2);
    __half* h2T     = (__half*)take((size_t)128 * 256 * 2);
    __half* att_h   = (__half*)take((size_t)LL * 256 * 2);
    float* biasLR   = (float*)take((size_t)LL * 512 * 4);
    __half* y1b = xr16;   // xr16 dead after layer-5 edge_k

    const int EB = (Etot + 255) / 256;
    const int NB = (N + 3) / 4;
    const int SB = (N + 255) / 256;    // 196 scan blocks

    // CSR build (cursor doubles as counts, then as scatter cursor after scanC)
    hipMemsetAsync(cursor, 0, (size_t)N * 4, stream);
    hist_k<<<EB, 256, 0, stream>>>(ei, E, N, cursor);
    scanA_k<<<SB, 256, 0, stream>>>(cursor, bsum, N);
    scanB_k<<<1, 256, 0, stream>>>(bsum, bpre, SB);
    scanC_k<<<SB, 256, 0, stream>>>(cursor, bpre, offsets, N, Etot);
    scatter_k<<<EB, 256, 0, stream>>>(ei, E, N, cursor, eidx);

    // fused prep: transposes(+gamma fold), biasfold(+beta fold), att cvt, softmax+suffix
    prep_k<<<243, 256, 0, stream>>>(win_w, Wl, Wr, h1_w, h2_w, ln_g, ln_b, bl, br, att, sw,
                                    winT, WlrT, h1T, h2T, att_h, biasLR, wsm);
    cvt_h_k<<<(N * 128 + 255) / 256, 256, 0, stream>>>(x, xh, N * 128);

    dim3 g2d((N + 127) / 128, 2);   // 391 x 2
    dim3 g4d((N + 127) / 128, 4);   // 391 x 4

    // entry: h16 = leaky(bn1(x @ win_w + win_b), 0.1) fp16; norm + hacc init
    gemm_h_k<1, 1><<<g2d, 256, 0, stream>>>(xh, winT, win_b, bn1_g, bn1_b, h16,
                                            nullptr, nullptr, N, 128, 256);
    ln_norm_k<<<NB, 256, 0, stream>>>(h16, hacc, norm, N);

    for (int l = 0; l < LL; ++l) {
        gemm_h_k<0, 2><<<g4d, 256, 0, stream>>>(norm, WlrT + (size_t)l * 131072,
                                                biasLR + l * 512, nullptr, nullptr,
                                                nullptr, xl8, xr16, N, 256, 512);
        edge_k<<<NB, 256, 0, stream>>>(xl8, xr16, att_h + l * 256, conv_b + l * 256,
                                       offsets, eidx, h16, hacc, norm,
                                       wsm, scales, l, N);
    }

    // exit MLP on hacc (= softmax-weighted layer sum, fp16)
    gemm_h_k<1, 1><<<g2d, 256, 0, stream>>>(hacc, h1T, h1_b, bn2_g, bn2_b, y1b,
                                            nullptr, nullptr, N, 256, 256);
    gemm_h_k<2, 0><<<dim3((N + 127) / 128, 1), 256, 0, stream>>>(
        y1b, h2T, h2_b, nullptr, nullptr, y2, nullptr, nullptr, N, 256, 128);
    out_k<<<NB, 256, 0, stream>>>(y2, h3_w, h3_b, (float*)d_out, N);
}

// Round 12
// 945.577 us; speedup vs baseline: 1.1535x; 1.0188x over previous
//
#include <hip/hip_runtime.h>
#include <hip/hip_fp16.h>

#define NN 50000
#define EE 800000
#define LL 6
constexpr float EPSF = 1e-5f;

typedef _Float16 f16x8 __attribute__((ext_vector_type(8)));
typedef _Float16 f16x2 __attribute__((ext_vector_type(2)));
typedef float f32x4 __attribute__((ext_vector_type(4)));
typedef unsigned short u16x8 __attribute__((ext_vector_type(8)));

__device__ __forceinline__ float leaky(float v, float s) { return v > 0.f ? v : s * v; }

__device__ __forceinline__ f16x2 asf2(unsigned int u) {
    union { unsigned int u; f16x2 f; } x; x.u = u; return x.f;
}
__device__ __forceinline__ unsigned int asu2(f16x2 f) {
    union { f16x2 f; unsigned int u; } x; x.f = f; return x.u;
}
__device__ __forceinline__ f16x2 lrelu2_02(f16x2 v) {
    return __builtin_elementwise_max(v, v * (_Float16)0.2f);
}
__device__ __forceinline__ f16x2 pk2(float a, float b) {
    f16x2 r; r[0] = (_Float16)a; r[1] = (_Float16)b; return r;
}
// fp32 -> one fp8 e4m3 byte
__device__ __forceinline__ unsigned char f2fp8(float v) {
    return (unsigned char)(__builtin_amdgcn_cvt_pk_fp8_f32(v, v, 0, false) & 0xff);
}

// async global->LDS, 16B per lane
#define GLD16(gp, sp) __builtin_amdgcn_global_load_lds( \
    (const __attribute__((address_space(1))) unsigned int*)(uintptr_t)(gp), \
    (__attribute__((address_space(3))) unsigned int*)(uintptr_t)(sp), 16, 0, 0)

// ------------- fused prep: transposes + biasfold + colsum + att cvt + softmax -------------
__global__ __launch_bounds__(256) void prep_k(
    const float* __restrict__ win_w, const float* __restrict__ Wl,
    const float* __restrict__ Wr, const float* __restrict__ h1_w,
    const float* __restrict__ h2_w, const float* __restrict__ ln_g,
    const float* __restrict__ ln_b, const float* __restrict__ bl,
    const float* __restrict__ br, const float* __restrict__ att,
    const float* __restrict__ sw,
    __half* __restrict__ winT, __half* __restrict__ WlrT,
    __half* __restrict__ h1T, __half* __restrict__ h2T,
    __half* __restrict__ att_h, float* __restrict__ biasLR,
    float* __restrict__ colsumLR, float* __restrict__ wsm)
{
    __shared__ float t[64][65];
    const int bid = blockIdx.x, tid = threadIdx.x;
    if (bid < 224) {
        const float* in; __half* out; const float* gamma = nullptr;
        int K, N, kb, nb;
        if (bid < 8)        { in = win_w; out = winT; K = 128; N = 256; kb = bid >> 2; nb = bid & 3; }
        else if (bid < 104) { int i = bid - 8; int l = i >> 4, r = i & 15;
            in = Wl + (size_t)l * 65536; out = WlrT + (size_t)l * 131072;
            gamma = ln_g + l * 256; K = 256; N = 256; kb = r >> 2; nb = r & 3; }
        else if (bid < 200) { int i = bid - 104; int l = i >> 4, r = i & 15;
            in = Wr + (size_t)l * 65536; out = WlrT + (size_t)l * 131072 + 65536;
            gamma = ln_g + l * 256; K = 256; N = 256; kb = r >> 2; nb = r & 3; }
        else if (bid < 216) { int i = bid - 200; in = h1_w; out = h1T; K = 256; N = 256; kb = i >> 2; nb = i & 3; }
        else                { int i = bid - 216; in = h2_w; out = h2T; K = 256; N = 128; kb = i >> 1; nb = i & 1; }
        const int k0 = kb * 64, n0 = nb * 64;
        {
            int kl = tid >> 2, np = (tid & 3) * 16;
            const float* ip = in + (size_t)(k0 + kl) * N + n0 + np;
            float4 a = *(const float4*)(ip + 0);
            float4 b = *(const float4*)(ip + 4);
            float4 c = *(const float4*)(ip + 8);
            float4 d = *(const float4*)(ip + 12);
            t[kl][np + 0] = a.x; t[kl][np + 1] = a.y; t[kl][np + 2] = a.z; t[kl][np + 3] = a.w;
            t[kl][np + 4] = b.x; t[kl][np + 5] = b.y; t[kl][np + 6] = b.z; t[kl][np + 7] = b.w;
            t[kl][np + 8] = c.x; t[kl][np + 9] = c.y; t[kl][np +10] = c.z; t[kl][np +11] = c.w;
            t[kl][np +12] = d.x; t[kl][np +13] = d.y; t[kl][np +14] = d.z; t[kl][np +15] = d.w;
        }
        __syncthreads();
        {
            int nl = tid >> 2, kp = (tid & 3) * 16;
            u16x8 o0, o1;
#pragma unroll
            for (int i = 0; i < 8; ++i) {
                float g0 = gamma ? gamma[k0 + kp + i] : 1.f;
                float g1 = gamma ? gamma[k0 + kp + 8 + i] : 1.f;
                o0[i] = __half_as_ushort(__float2half(t[kp + i][nl] * g0));
                o1[i] = __half_as_ushort(__float2half(t[kp + 8 + i][nl] * g1));
            }
            unsigned short* op = (unsigned short*)out + (size_t)(n0 + nl) * K + k0 + kp;
            *(u16x8*)(op + 0) = o0;
            *(u16x8*)(op + 8) = o1;
        }
    } else if (bid < 236) {
        int i = bid - 224, l = i >> 1, side = i & 1, n = tid;
        const float* W = side ? Wr : Wl;
        const float* b = side ? br : bl;
        const float* lb = ln_b + l * 256;
        const float* lg = ln_g + l * 256;
        const float* Wp = W + (size_t)l * 65536;
        float accb = b[l * 256 + n];
        float accc = 0.f;
        for (int k = 0; k < 256; ++k) {
            float wv = Wp[(size_t)k * 256 + n];
            accb = fmaf(lb[k], wv, accb);
            accc = fmaf(lg[k], wv, accc);
        }
        biasLR[l * 512 + side * 256 + n] = accb;
        colsumLR[l * 512 + side * 256 + n] = accc;
    } else if (bid < 242) {
        int l = bid - 236;
        att_h[l * 256 + tid] = __float2half(att[l * 256 + tid]);
    } else if (tid == 0) {
        float m = -1e30f;
        for (int l = 0; l < LL; ++l) m = fmaxf(m, sw[l]);
        float e[LL]; float s = 0.f;
        for (int l = 0; l < LL; ++l) { e[l] = __expf(sw[l] - m); s += e[l]; }
        float w[LL];
        for (int l = 0; l < LL; ++l) { w[l] = e[l] / s; wsm[l] = w[l]; }
        for (int l = 0; l < LL; ++l) {
            float S = 0.f;
            for (int k = l; k < LL; ++k) S += w[k];
            wsm[8 + l] = S;   // suffix sums
        }
    }
}

// ------- generic fp32 -> fp16 -------
__global__ __launch_bounds__(256) void cvt_h_k(const float* __restrict__ in,
                                               __half* __restrict__ out, int n)
{
    int i = blockIdx.x * 256 + threadIdx.x;
    if (i < n) out[i] = __float2half(in[i]);
}

// ------- fp16 MFMA GEMM, 128x128 tile, BK=64, global_load_lds staging, XOR swizzle ----
// ACT 1: +bias, bn, leaky. ACT 2: +bias, leaky. ACT 3: LN epilogue
//   v = rs[row]*acc - rs[row]*mu[row]*colsum[c] + bias[c]   (LN folded via colsum)
// OUT: 0 = fp32 Cv, 1 = fp16 Cv, 2 = split (bn==0 panel -> fp8 C8, bn==256.. -> fp16 C16)
template<int ACT, int OUT>
__global__ __launch_bounds__(256) void gemm_h_k(
    const __half* __restrict__ A, const __half* __restrict__ Bt,
    const float* __restrict__ bias, const float* __restrict__ g2,
    const float* __restrict__ b2,
    const float* __restrict__ mu, const float* __restrict__ rsig,
    const float* __restrict__ colsum,
    void* __restrict__ Cv, unsigned char* __restrict__ C8, __half* __restrict__ C16,
    int M, int K, int N)
{
    __shared__ _Float16 As[128 * 64];
    __shared__ _Float16 Bs[128 * 64];
    const int tid = threadIdx.x, lane = tid & 63, wave = tid >> 6;
    const int bm = blockIdx.x * 128, bn = blockIdx.y * 128;
    const int wm = (wave & 1) * 64, wn = (wave >> 1) * 64;
    const int mrow = lane & 15;
    const int sg = lane >> 3;
    const int sc = (lane & 7) ^ sg;

    f32x4 acc[4][4];
#pragma unroll
    for (int i = 0; i < 4; ++i)
#pragma unroll
        for (int j = 0; j < 4; ++j) acc[i][j] = (f32x4){0.f, 0.f, 0.f, 0.f};

    for (int k0 = 0; k0 < K; k0 += 64) {
#pragma unroll
        for (int t = 0; t < 4; ++t) {
            int R = 32 * wave + 8 * t;
            int ar = bm + R + sg; if (ar >= M) ar = M - 1;
            GLD16(A + (size_t)ar * K + k0 + sc * 8, &As[R * 64]);
        }
#pragma unroll
        for (int t = 0; t < 4; ++t) {
            int R = 32 * wave + 8 * t;
            GLD16(Bt + (size_t)(bn + R + sg) * K + k0 + sc * 8, &Bs[R * 64]);
        }
        __syncthreads();
#pragma unroll
        for (int s2 = 0; s2 < 2; ++s2) {
            const int c = s2 * 4 + (lane >> 4);
            f16x8 af[4], bf[4];
#pragma unroll
            for (int i = 0; i < 4; ++i) {
                int r = wm + 16 * i + mrow;
                af[i] = *(const f16x8*)&As[r * 64 + ((c ^ (r & 7)) * 8)];
            }
#pragma unroll
            for (int j = 0; j < 4; ++j) {
                int r = wn + 16 * j + mrow;
                bf[j] = *(const f16x8*)&Bs[r * 64 + ((c ^ (r & 7)) * 8)];
            }
#pragma unroll
            for (int i = 0; i < 4; ++i)
#pragma unroll
                for (int j = 0; j < 4; ++j)
                    acc[i][j] = __builtin_amdgcn_mfma_f32_16x16x32_f16(af[i], bf[j], acc[i][j], 0, 0, 0);
        }
        __syncthreads();
    }

    const float inv_s = 0.9999950000374997f; // 1/sqrt(1+1e-5)
    const int rq = (lane >> 4) * 4;
    float bsj[4], gj[4], bbj[4], csj[4];
#pragma unroll
    for (int j = 0; j < 4; ++j) {
        int cc = bn + wn + 16 * j + mrow;
        bsj[j] = bias[cc];
        if constexpr (ACT == 1) { gj[j] = g2[cc]; bbj[j] = b2[cc]; }
        if constexpr (ACT == 3) { csj[j] = colsum[cc]; }
    }
#pragma unroll
    for (int i = 0; i < 4; ++i)
#pragma unroll
        for (int r = 0; r < 4; ++r) {
            int grow = bm + wm + 16 * i + rq + r;
            if (grow >= M) continue;
            float rsv = 0.f, rmu = 0.f;
            if constexpr (ACT == 3) { rsv = rsig[grow]; rmu = rsv * mu[grow]; }
#pragma unroll
            for (int j = 0; j < 4; ++j) {
                int cc = bn + wn + 16 * j + mrow;
                float v;
                if constexpr (ACT == 3) v = fmaf(rsv, acc[i][j][r], fmaf(-rmu, csj[j], bsj[j]));
                else v = acc[i][j][r] + bsj[j];
                if constexpr (ACT == 1) v = leaky(v * inv_s * gj[j] + bbj[j], 0.1f);
                else if constexpr (ACT == 2) v = leaky(v, 0.1f);
                if constexpr (OUT == 0)      ((float*)Cv)[(size_t)grow * N + cc] = v;
                else if constexpr (OUT == 1) ((__half*)Cv)[(size_t)grow * N + cc] = __float2half(v);
                else {
                    if (bn < 256) C8[(size_t)grow * 256 + cc] = f2fp8(v);
                    else          C16[(size_t)grow * 256 + (cc - 256)] = __float2half(v);
                }
            }
        }
}

// ------- entry LN stats: mu/rsig of h16; hacc init = h16 -------
__global__ __launch_bounds__(256) void ln_stats_k(const __half* __restrict__ h16,
                                                  __half* __restrict__ hacc,
                                                  float* __restrict__ mu,
                                                  float* __restrict__ rsig, int N)
{
    int wv = blockIdx.x * 4 + (threadIdx.x >> 6);
    if (wv >= N) return;
    int lane = threadIdx.x & 63;
    size_t off = (size_t)wv * 256 + lane * 4;
    uint2 u = *(const uint2*)((const unsigned short*)h16 + off);
    f16x2 p0 = asf2(u.x), p1 = asf2(u.y);
    float v0 = (float)p0[0], v1 = (float)p0[1], v2 = (float)p1[0], v3 = (float)p1[1];
    float s = v0 + v1 + v2 + v3;
#pragma unroll
    for (int o = 1; o < 64; o <<= 1) s += __shfl_xor(s, o);
    float m = s * (1.f / 256.f);
    float d0 = v0 - m, d1 = v1 - m, d2 = v2 - m, d3 = v3 - m;
    float q = d0 * d0 + d1 * d1 + d2 * d2 + d3 * d3;
#pragma unroll
    for (int o = 1; o < 64; o <<= 1) q += __shfl_xor(q, o);
    float rs = rsqrtf(q * (1.f / 256.f) + EPSF);
    *(uint2*)((unsigned short*)hacc + off) = u;
    if (lane == 0) { mu[wv] = m; rsig[wv] = rs; }
}

// ---------------- CSR build ----------------
__global__ __launch_bounds__(256) void hist_k(const int* __restrict__ ei, int E, int N,
                                              int* __restrict__ counts)
{
    int e = blockIdx.x * 256 + threadIdx.x;
    int Etot = E + N;
    if (e >= Etot) return;
    int d = (e < E) ? ei[E + e] : (e - E);
    atomicAdd(&counts[d], 1);
}

// ---- 3-phase grid scan ----
__global__ __launch_bounds__(256) void scanA_k(const int* __restrict__ counts,
                                               int* __restrict__ bsum, int N)
{
    int i = blockIdx.x * 256 + threadIdx.x;
    int v = (i < N) ? counts[i] : 0;
    int s = v;
#pragma unroll
    for (int o = 1; o < 64; o <<= 1) s += __shfl_xor(s, o);
    __shared__ int ws[4];
    if ((threadIdx.x & 63) == 0) ws[threadIdx.x >> 6] = s;
    __syncthreads();
    if (threadIdx.x == 0) bsum[blockIdx.x] = ws[0] + ws[1] + ws[2] + ws[3];
}

__global__ __launch_bounds__(256) void scanB_k(const int* __restrict__ bsum,
                                               int* __restrict__ bpre, int nb)
{
    int t = threadIdx.x;
    int v = (t < nb) ? bsum[t] : 0;
    int lane = t & 63, w = t >> 6;
    int incl = v;
#pragma unroll
    for (int o = 1; o < 64; o <<= 1) { int u = __shfl_up(incl, o); if (lane >= o) incl += u; }
    __shared__ int ws[4];
    if (lane == 63) ws[w] = incl;
    __syncthreads();
    if (t == 0) { int run = 0; for (int k = 0; k < 4; ++k) { int x = ws[k]; ws[k] = run; run += x; } }
    __syncthreads();
    if (t < nb) bpre[t] = ws[w] + incl - v;
}

__global__ __launch_bounds__(256) void scanC_k(int* __restrict__ counts,
                                               const int* __restrict__ bpre,
                                               int* __restrict__ offsets, int N, int Etot)
{
    int i = blockIdx.x * 256 + threadIdx.x;
    int v = (i < N) ? counts[i] : 0;
    int lane = threadIdx.x & 63, w = threadIdx.x >> 6;
    int incl = v;
#pragma unroll
    for (int o = 1; o < 64; o <<= 1) { int u = __shfl_up(incl, o); if (lane >= o) incl += u; }
    __shared__ int ws[4];
    if (lane == 63) ws[w] = incl;
    __syncthreads();
    if (threadIdx.x == 0) { int run = 0; for (int k = 0; k < 4; ++k) { int x = ws[k]; ws[k] = run; run += x; } }
    __syncthreads();
    int ex = bpre[blockIdx.x] + ws[w] + incl - v;
    if (i < N) { offsets[i] = ex; counts[i] = ex; }   // counts becomes the scatter cursor
    if (i == 0) offsets[N] = Etot;
}

__global__ __launch_bounds__(256) void scatter_k(const int* __restrict__ ei, int E, int N,
                                                 int* __restrict__ cursor, int* __restrict__ eidx)
{
    int e = blockIdx.x * 256 + threadIdx.x;
    int Etot = E + N;
    if (e >= Etot) return;
    int s, d;
    if (e < E) { s = ei[e]; d = ei[E + e]; }
    else       { s = e - E; d = s; }
    int pos = atomicAdd(&cursor[d], 1);
    eidx[pos] = s;
}

// ------- Edge aggregation: wave/node, 4 slots x 16 lanes x 16 ch; fp8 xl gather -------
__global__ __launch_bounds__(256) void edge_k(
    const unsigned char* __restrict__ xl8, const __half* __restrict__ xr16,
    const __half* __restrict__ atth, const float* __restrict__ convb,
    const int* __restrict__ offsets, const int* __restrict__ eidx,
    __half* __restrict__ h16, __half* __restrict__ hacc,
    float* __restrict__ mu, float* __restrict__ rsig,
    const float* __restrict__ wsm, const float* __restrict__ scales,
    int layer, int N)
{
    int wv = blockIdx.x * 4 + (threadIdx.x >> 6);
    if (wv >= N) return;
    const int lane = threadIdx.x & 63;
    const int slot = lane >> 4, sl = lane & 15;
    const int c0 = sl * 16;               // this lane's 16-channel segment (head = sl>>1)

    f16x2 atv[8], xrv[8];
    {
        const unsigned short* ap = (const unsigned short*)atth + c0;
        const unsigned short* xp = (const unsigned short*)xr16 + (size_t)wv * 256 + c0;
        uint4 a0 = *(const uint4*)ap, a1 = *(const uint4*)(ap + 8);
        uint4 x0 = *(const uint4*)xp, x1 = *(const uint4*)(xp + 8);
        atv[0]=asf2(a0.x); atv[1]=asf2(a0.y); atv[2]=asf2(a0.z); atv[3]=asf2(a0.w);
        atv[4]=asf2(a1.x); atv[5]=asf2(a1.y); atv[6]=asf2(a1.z); atv[7]=asf2(a1.w);
        xrv[0]=asf2(x0.x); xrv[1]=asf2(x0.y); xrv[2]=asf2(x0.z); xrv[3]=asf2(x0.w);
        xrv[4]=asf2(x1.x); xrv[5]=asf2(x1.y); xrv[6]=asf2(x1.z); xrv[7]=asf2(x1.w);
    }
    const int e0 = offsets[wv], e1 = offsets[wv + 1], e1m = e1 - 1;
    f16x2 a2[8];
#pragma unroll
    for (int p = 0; p < 8; ++p) a2[p] = pk2(0.f, 0.f);
    float den = 0.f;

    for (int base = e0; base < e1; base += 4) {
        int e = base + slot;
        bool v = e < e1;
        int s = eidx[v ? e : e1m];
        uint4 w = *(const uint4*)(xl8 + (size_t)s * 256 + c0);   // 16 fp8 ch
        f16x2 xv[8];
        xv[0] = __builtin_amdgcn_cvt_scalef32_pk_f16_fp8(w.x, 1.0f, false);
        xv[1] = __builtin_amdgcn_cvt_scalef32_pk_f16_fp8(w.x, 1.0f, true);
        xv[2] = __builtin_amdgcn_cvt_scalef32_pk_f16_fp8(w.y, 1.0f, false);
        xv[3] = __builtin_amdgcn_cvt_scalef32_pk_f16_fp8(w.y, 1.0f, true);
        xv[4] = __builtin_amdgcn_cvt_scalef32_pk_f16_fp8(w.z, 1.0f, false);
        xv[5] = __builtin_amdgcn_cvt_scalef32_pk_f16_fp8(w.z, 1.0f, true);
        xv[6] = __builtin_amdgcn_cvt_scalef32_pk_f16_fp8(w.w, 1.0f, false);
        xv[7] = __builtin_amdgcn_cvt_scalef32_pk_f16_fp8(w.w, 1.0f, true);
        float pm = 0.f;
#pragma unroll
        for (int p = 0; p < 8; ++p) {
            f16x2 t = lrelu2_02(xv[p] + xrv[p]);
            pm = __builtin_amdgcn_fdot2(t, atv[p], pm, false);
        }
        pm += __shfl_xor(pm, 1);             // head = 2 lanes (32 ch)
        float exf = v ? __expf(pm) : 0.f;
        den += exf;
        _Float16 eh = (_Float16)exf;
        f16x2 e2; e2[0] = eh; e2[1] = eh;
#pragma unroll
        for (int p = 0; p < 8; ++p) a2[p] += xv[p] * e2;
    }

    // combine across the 4 slots (lane bits 4,5)
    den += __shfl_xor(den, 16); den += __shfl_xor(den, 32);
#pragma unroll
    for (int p = 0; p < 8; ++p) {
        a2[p] += asf2((unsigned int)__shfl_xor((int)asu2(a2[p]), 16));
        a2[p] += asf2((unsigned int)__shfl_xor((int)asu2(a2[p]), 32));
    }

    // all-lane epilogue: lane handles 4 channels cc = c0 + 4*slot (a2[2*slot], a2[2*slot+1])
    const int p0 = 2 * slot;
    const float inv = 1.f / den;
    const float sc = scales[layer], Sl = wsm[8 + layer];
    const int cc = c0 + 4 * slot;
    const size_t rb = (size_t)wv * 256 + cc;
    float4 cb = *(const float4*)(convb + cc);
    uint2 hu = *(const uint2*)((const unsigned short*)h16 + rb);
    f16x2 h0 = asf2(hu.x), h1 = asf2(hu.y);
    float d00 = sc * leaky(fmaf((float)a2[p0][0],     inv, cb.x), 0.1f);
    float d01 = sc * leaky(fmaf((float)a2[p0][1],     inv, cb.y), 0.1f);
    float d10 = sc * leaky(fmaf((float)a2[p0 + 1][0], inv, cb.z), 0.1f);
    float d11 = sc * leaky(fmaf((float)a2[p0 + 1][1], inv, cb.w), 0.1f);
    float hn0 = (float)h0[0] + d00, hn1 = (float)h0[1] + d01;
    float hn2 = (float)h1[0] + d10, hn3 = (float)h1[1] + d11;

    // hacc += S_l * d   (hsum = h_entry + sum_l S_l d_l; softmax weights sum to 1)
    {
        uint2 au = *(const uint2*)((const unsigned short*)hacc + rb);
        f16x2 A0 = asf2(au.x), A1 = asf2(au.y);
        uint2 ao;
        ao.x = asu2(pk2(fmaf(Sl, d00, (float)A0[0]), fmaf(Sl, d01, (float)A0[1])));
        ao.y = asu2(pk2(fmaf(Sl, d10, (float)A1[0]), fmaf(Sl, d11, (float)A1[1])));
        *(uint2*)((unsigned short*)hacc + rb) = ao;
    }

    if (layer != LL - 1) {
        uint2 ho;
        ho.x = asu2(pk2(hn0, hn1));
        ho.y = asu2(pk2(hn2, hn3));
        *(uint2*)((unsigned short*)h16 + rb) = ho;
        // LN stats across the full wave (each lane holds 4 distinct channels)
        float s1 = hn0 + hn1 + hn2 + hn3;
#pragma unroll
        for (int o = 1; o < 64; o <<= 1) s1 += __shfl_xor(s1, o);
        float m = s1 * (1.f / 256.f);
        float dd0 = hn0 - m, dd1 = hn1 - m, dd2 = hn2 - m, dd3 = hn3 - m;
        float qv = dd0 * dd0 + dd1 * dd1 + dd2 * dd2 + dd3 * dd3;
#pragma unroll
        for (int o = 1; o < 64; o <<= 1) qv += __shfl_xor(qv, o);
        float rs = rsqrtf(qv * (1.f / 256.f) + EPSF);
        if (lane == 0) { mu[wv] = m; rsig[wv] = rs; }
    }
}

// ---------------- final y2[N,128] @ h3_w[128,1] + h3_b ----------------
__global__ __launch_bounds__(256) void out_k(const float* __restrict__ y2,
                                             const float* __restrict__ w,
                                             const float* __restrict__ b,
                                             float* __restrict__ out, int N)
{
    int wv = blockIdx.x * 4 + (threadIdx.x >> 6);
    if (wv >= N) return;
    int lane = threadIdx.x & 63;
    float2 v = *(const float2*)(y2 + (size_t)wv * 128 + lane * 2);
    float2 ww = *(const float2*)(w + lane * 2);
    float pm = v.x * ww.x + v.y * ww.y;
#pragma unroll
    for (int off = 1; off < 64; off <<= 1) pm += __shfl_xor(pm, off);
    if (lane == 0) out[wv] = pm + b[0];
}

extern "C" void kernel_launch(void* const* d_in, const int* in_sizes, int n_in,
                              void* d_out, int out_size, void* d_ws, size_t ws_size,
                              hipStream_t stream)
{
    const int N = NN, E = EE, Etot = EE + NN;
    const float* x      = (const float*)d_in[0];
    const int*   ei     = (const int*)  d_in[1];
    const float* win_w  = (const float*)d_in[2];
    const float* win_b  = (const float*)d_in[3];
    const float* bn1_g  = (const float*)d_in[4];
    const float* bn1_b  = (const float*)d_in[5];
    const float* ln_g   = (const float*)d_in[6];
    const float* ln_b   = (const float*)d_in[7];
    const float* Wl     = (const float*)d_in[8];
    const float* bl     = (const float*)d_in[9];
    const float* Wr     = (const float*)d_in[10];
    const float* br     = (const float*)d_in[11];
    const float* att    = (const float*)d_in[12];
    const float* conv_b = (const float*)d_in[13];
    const float* scales = (const float*)d_in[14];
    const float* sw     = (const float*)d_in[15];
    const float* h1_w   = (const float*)d_in[16];
    const float* h1_b   = (const float*)d_in[17];
    const float* bn2_g  = (const float*)d_in[18];
    const float* bn2_b  = (const float*)d_in[19];
    const float* h2_w   = (const float*)d_in[20];
    const float* h2_b   = (const float*)d_in[21];
    const float* h3_w   = (const float*)d_in[22];
    const float* h3_b   = (const float*)d_in[23];

    char* p = (char*)d_ws;
    auto take = [&](size_t b) -> char* {
        char* q = p; p += (b + 255) & ~(size_t)255; return q;
    };
    __half* h16     = (__half*)take((size_t)N * 256 * 2);
    __half* hacc    = (__half*)take((size_t)N * 256 * 2);
    float*  mu      = (float*)take((size_t)N * 4);
    float*  rsig    = (float*)take((size_t)N * 4);
    unsigned char* xl8 = (unsigned char*)take((size_t)N * 256);
    __half* xr16    = (__half*)take((size_t)N * 256 * 2);
    __half* xh      = (__half*)take((size_t)N * 128 * 2);
    float*  y2      = (float*)take((size_t)N * 128 * 4);
    float* wsm      = (float*)take(256);
    int*   offsets  = (int*)take((size_t)(N + 1) * 4);
    int*   cursor   = (int*)take((size_t)N * 4);
    int*   eidx     = (int*)take((size_t)Etot * 4);
    int*   bsum     = (int*)take(256 * 4);
    int*   bpre     = (int*)take(256 * 4);
    __half* winT    = (__half*)take((size_t)256 * 128 * 2);
    __half* WlrT    = (__half*)take((size_t)LL * 512 * 256 * 2);
    __half* h1T     = (__half*)take((size_t)256 * 256 * 2);
    __half* h2T     = (__half*)take((size_t)128 * 256 * 2);
    __half* att_h   = (__half*)take((size_t)LL * 256 * 2);
    float* biasLR   = (float*)take((size_t)LL * 512 * 4);
    float* colsumLR = (float*)take((size_t)LL * 512 * 4);
    __half* y1b = xr16;   // xr16 dead after layer-5 edge_k

    const int EB = (Etot + 255) / 256;
    const int NB = (N + 3) / 4;
    const int SB = (N + 255) / 256;    // 196 scan blocks

    // CSR build (cursor doubles as counts, then as scatter cursor after scanC)
    hipMemsetAsync(cursor, 0, (size_t)N * 4, stream);
    hist_k<<<EB, 256, 0, stream>>>(ei, E, N, cursor);
    scanA_k<<<SB, 256, 0, stream>>>(cursor, bsum, N);
    scanB_k<<<1, 256, 0, stream>>>(bsum, bpre, SB);
    scanC_k<<<SB, 256, 0, stream>>>(cursor, bpre, offsets, N, Etot);
    scatter_k<<<EB, 256, 0, stream>>>(ei, E, N, cursor, eidx);

    // fused prep: transposes(+gamma fold), biasfold(+beta fold), colsum, att cvt, softmax
    prep_k<<<243, 256, 0, stream>>>(win_w, Wl, Wr, h1_w, h2_w, ln_g, ln_b, bl, br, att, sw,
                                    winT, WlrT, h1T, h2T, att_h, biasLR, colsumLR, wsm);
    cvt_h_k<<<(N * 128 + 255) / 256, 256, 0, stream>>>(x, xh, N * 128);

    dim3 g2d((N + 127) / 128, 2);   // 391 x 2
    dim3 g4d((N + 127) / 128, 4);   // 391 x 4

    // entry: h16 = leaky(bn1(x @ win_w + win_b), 0.1) fp16; stats + hacc init
    gemm_h_k<1, 1><<<g2d, 256, 0, stream>>>(xh, winT, win_b, bn1_g, bn1_b,
                                            nullptr, nullptr, nullptr,
                                            h16, nullptr, nullptr, N, 128, 256);
    ln_stats_k<<<NB, 256, 0, stream>>>(h16, hacc, mu, rsig, N);

    for (int l = 0; l < LL; ++l) {
        // xl8/xr16 = LN(h16) @ WlrT + biasLR, LN applied in epilogue via colsum identity
        gemm_h_k<3, 2><<<g4d, 256, 0, stream>>>(h16, WlrT + (size_t)l * 131072,
                                                biasLR + l * 512, nullptr, nullptr,
                                                mu, rsig, colsumLR + l * 512,
                                                nullptr, xl8, xr16, N, 256, 512);
        edge_k<<<NB, 256, 0, stream>>>(xl8, xr16, att_h + l * 256, conv_b + l * 256,
                                       offsets, eidx, h16, hacc, mu, rsig,
                                       wsm, scales, l, N);
    }

    // exit MLP on hacc (= softmax-weighted layer sum, fp16)
    gemm_h_k<1, 1><<<g2d, 256, 0, stream>>>(hacc, h1T, h1_b, bn2_g, bn2_b,
                                            nullptr, nullptr, nullptr,
                                            y1b, nullptr, nullptr, N, 256, 256);
    gemm_h_k<2, 0><<<dim3((N + 127) / 128, 1), 256, 0, stream>>>(
        y1b, h2T, h2_b, nullptr, nullptr, nullptr, nullptr, nullptr,
        y2, nullptr, nullptr, N, 256, 128);
    out_k<<<NB, 256, 0, stream>>>(y2, h3_w, h3_b, (float*)d_out, N);
}

// Round 13
// 922.063 us; speedup vs baseline: 1.1830x; 1.0255x over previous
//
#include <hip/hip_runtime.h>
#include <hip/hip_fp16.h>

#define NN 50000
#define EE 800000
#define LL 6
constexpr float EPSF = 1e-5f;

typedef _Float16 f16x8 __attribute__((ext_vector_type(8)));
typedef _Float16 f16x2 __attribute__((ext_vector_type(2)));
typedef float f32x4 __attribute__((ext_vector_type(4)));
typedef unsigned short u16x8 __attribute__((ext_vector_type(8)));

__device__ __forceinline__ float leaky(float v, float s) { return v > 0.f ? v : s * v; }

__device__ __forceinline__ f16x2 asf2(unsigned int u) {
    union { unsigned int u; f16x2 f; } x; x.u = u; return x.f;
}
__device__ __forceinline__ unsigned int asu2(f16x2 f) {
    union { f16x2 f; unsigned int u; } x; x.f = f; return x.u;
}
__device__ __forceinline__ f16x2 lrelu2_02(f16x2 v) {
    return __builtin_elementwise_max(v, v * (_Float16)0.2f);
}
__device__ __forceinline__ f16x2 pk2(float a, float b) {
    f16x2 r; r[0] = (_Float16)a; r[1] = (_Float16)b; return r;
}
// fp32 -> one fp8 e4m3 byte
__device__ __forceinline__ unsigned char f2fp8(float v) {
    return (unsigned char)(__builtin_amdgcn_cvt_pk_fp8_f32(v, v, 0, false) & 0xff);
}

// async global->LDS, 16B per lane
#define GLD16(gp, sp) __builtin_amdgcn_global_load_lds( \
    (const __attribute__((address_space(1))) unsigned int*)(uintptr_t)(gp), \
    (__attribute__((address_space(3))) unsigned int*)(uintptr_t)(sp), 16, 0, 0)

// ------ fused prep: transposes + biasfold + colsum + att cvt + softmax + x->fp16 ------
__global__ __launch_bounds__(256) void prep_k(
    const float* __restrict__ win_w, const float* __restrict__ Wl,
    const float* __restrict__ Wr, const float* __restrict__ h1_w,
    const float* __restrict__ h2_w, const float* __restrict__ ln_g,
    const float* __restrict__ ln_b, const float* __restrict__ bl,
    const float* __restrict__ br, const float* __restrict__ att,
    const float* __restrict__ sw, const float* __restrict__ x,
    __half* __restrict__ xh,
    __half* __restrict__ winT, __half* __restrict__ WlrT,
    __half* __restrict__ h1T, __half* __restrict__ h2T,
    __half* __restrict__ att_h, float* __restrict__ biasLR,
    float* __restrict__ colsumLR, float* __restrict__ wsm)
{
    __shared__ float t[64][65];
    const int bid = blockIdx.x, tid = threadIdx.x;
    if (bid >= 243) {   // x -> fp16 conversion blocks
        int i = (bid - 243) * 256 + tid;
        if (i < NN * 128) xh[i] = __float2half(x[i]);
        return;
    }
    if (bid < 224) {
        const float* in; __half* out; const float* gamma = nullptr;
        int K, N, kb, nb;
        if (bid < 8)        { in = win_w; out = winT; K = 128; N = 256; kb = bid >> 2; nb = bid & 3; }
        else if (bid < 104) { int i = bid - 8; int l = i >> 4, r = i & 15;
            in = Wl + (size_t)l * 65536; out = WlrT + (size_t)l * 131072;
            gamma = ln_g + l * 256; K = 256; N = 256; kb = r >> 2; nb = r & 3; }
        else if (bid < 200) { int i = bid - 104; int l = i >> 4, r = i & 15;
            in = Wr + (size_t)l * 65536; out = WlrT + (size_t)l * 131072 + 65536;
            gamma = ln_g + l * 256; K = 256; N = 256; kb = r >> 2; nb = r & 3; }
        else if (bid < 216) { int i = bid - 200; in = h1_w; out = h1T; K = 256; N = 256; kb = i >> 2; nb = i & 3; }
        else                { int i = bid - 216; in = h2_w; out = h2T; K = 256; N = 128; kb = i >> 1; nb = i & 1; }
        const int k0 = kb * 64, n0 = nb * 64;
        {
            int kl = tid >> 2, np = (tid & 3) * 16;
            const float* ip = in + (size_t)(k0 + kl) * N + n0 + np;
            float4 a = *(const float4*)(ip + 0);
            float4 b = *(const float4*)(ip + 4);
            float4 c = *(const float4*)(ip + 8);
            float4 d = *(const float4*)(ip + 12);
            t[kl][np + 0] = a.x; t[kl][np + 1] = a.y; t[kl][np + 2] = a.z; t[kl][np + 3] = a.w;
            t[kl][np + 4] = b.x; t[kl][np + 5] = b.y; t[kl][np + 6] = b.z; t[kl][np + 7] = b.w;
            t[kl][np + 8] = c.x; t[kl][np + 9] = c.y; t[kl][np +10] = c.z; t[kl][np +11] = c.w;
            t[kl][np +12] = d.x; t[kl][np +13] = d.y; t[kl][np +14] = d.z; t[kl][np +15] = d.w;
        }
        __syncthreads();
        {
            int nl = tid >> 2, kp = (tid & 3) * 16;
            u16x8 o0, o1;
#pragma unroll
            for (int i = 0; i < 8; ++i) {
                float g0 = gamma ? gamma[k0 + kp + i] : 1.f;
                float g1 = gamma ? gamma[k0 + kp + 8 + i] : 1.f;
                o0[i] = __half_as_ushort(__float2half(t[kp + i][nl] * g0));
                o1[i] = __half_as_ushort(__float2half(t[kp + 8 + i][nl] * g1));
            }
            unsigned short* op = (unsigned short*)out + (size_t)(n0 + nl) * K + k0 + kp;
            *(u16x8*)(op + 0) = o0;
            *(u16x8*)(op + 8) = o1;
        }
    } else if (bid < 236) {
        int i = bid - 224, l = i >> 1, side = i & 1, n = tid;
        const float* W = side ? Wr : Wl;
        const float* b = side ? br : bl;
        const float* lb = ln_b + l * 256;
        const float* lg = ln_g + l * 256;
        const float* Wp = W + (size_t)l * 65536;
        float accb = b[l * 256 + n];
        float accc = 0.f;
        for (int k = 0; k < 256; ++k) {
            float wv = Wp[(size_t)k * 256 + n];
            accb = fmaf(lb[k], wv, accb);
            accc = fmaf(lg[k], wv, accc);
        }
        biasLR[l * 512 + side * 256 + n] = accb;
        colsumLR[l * 512 + side * 256 + n] = accc;
    } else if (bid < 242) {
        int l = bid - 236;
        att_h[l * 256 + tid] = __float2half(att[l * 256 + tid]);
    } else if (tid == 0) {
        float m = -1e30f;
        for (int l = 0; l < LL; ++l) m = fmaxf(m, sw[l]);
        float e[LL]; float s = 0.f;
        for (int l = 0; l < LL; ++l) { e[l] = __expf(sw[l] - m); s += e[l]; }
        float w[LL];
        for (int l = 0; l < LL; ++l) { w[l] = e[l] / s; wsm[l] = w[l]; }
        for (int l = 0; l < LL; ++l) {
            float S = 0.f;
            for (int k = l; k < LL; ++k) S += w[k];
            wsm[8 + l] = S;   // suffix sums
        }
    }
}

// ------- fp16 MFMA GEMM, 128x128 tile, BK=64, global_load_lds staging, XOR swizzle ----
// ACT 1: +bias, bn, leaky. ACT 2: +bias, leaky. ACT 3: LN epilogue via colsum identity.
// OUT: 0 = fp32 Cv, 1 = fp16 Cv, 2 = split (bn==0 panel -> fp8 C8, bn==256.. -> fp16 C16)
template<int ACT, int OUT>
__global__ __launch_bounds__(256) void gemm_h_k(
    const __half* __restrict__ A, const __half* __restrict__ Bt,
    const float* __restrict__ bias, const float* __restrict__ g2,
    const float* __restrict__ b2,
    const float* __restrict__ mu, const float* __restrict__ rsig,
    const float* __restrict__ colsum,
    void* __restrict__ Cv, unsigned char* __restrict__ C8, __half* __restrict__ C16,
    int M, int K, int N)
{
    __shared__ _Float16 As[128 * 64];
    __shared__ _Float16 Bs[128 * 64];
    const int tid = threadIdx.x, lane = tid & 63, wave = tid >> 6;
    const int bm = blockIdx.x * 128, bn = blockIdx.y * 128;
    const int wm = (wave & 1) * 64, wn = (wave >> 1) * 64;
    const int mrow = lane & 15;
    const int sg = lane >> 3;
    const int sc = (lane & 7) ^ sg;

    f32x4 acc[4][4];
#pragma unroll
    for (int i = 0; i < 4; ++i)
#pragma unroll
        for (int j = 0; j < 4; ++j) acc[i][j] = (f32x4){0.f, 0.f, 0.f, 0.f};

    for (int k0 = 0; k0 < K; k0 += 64) {
#pragma unroll
        for (int t = 0; t < 4; ++t) {
            int R = 32 * wave + 8 * t;
            int ar = bm + R + sg; if (ar >= M) ar = M - 1;
            GLD16(A + (size_t)ar * K + k0 + sc * 8, &As[R * 64]);
        }
#pragma unroll
        for (int t = 0; t < 4; ++t) {
            int R = 32 * wave + 8 * t;
            GLD16(Bt + (size_t)(bn + R + sg) * K + k0 + sc * 8, &Bs[R * 64]);
        }
        __syncthreads();
#pragma unroll
        for (int s2 = 0; s2 < 2; ++s2) {
            const int c = s2 * 4 + (lane >> 4);
            f16x8 af[4], bf[4];
#pragma unroll
            for (int i = 0; i < 4; ++i) {
                int r = wm + 16 * i + mrow;
                af[i] = *(const f16x8*)&As[r * 64 + ((c ^ (r & 7)) * 8)];
            }
#pragma unroll
            for (int j = 0; j < 4; ++j) {
                int r = wn + 16 * j + mrow;
                bf[j] = *(const f16x8*)&Bs[r * 64 + ((c ^ (r & 7)) * 8)];
            }
#pragma unroll
            for (int i = 0; i < 4; ++i)
#pragma unroll
                for (int j = 0; j < 4; ++j)
                    acc[i][j] = __builtin_amdgcn_mfma_f32_16x16x32_f16(af[i], bf[j], acc[i][j], 0, 0, 0);
        }
        __syncthreads();
    }

    const float inv_s = 0.9999950000374997f; // 1/sqrt(1+1e-5)
    const int rq = (lane >> 4) * 4;
    float bsj[4], gj[4], bbj[4], csj[4];
#pragma unroll
    for (int j = 0; j < 4; ++j) {
        int cc = bn + wn + 16 * j + mrow;
        bsj[j] = bias[cc];
        if constexpr (ACT == 1) { gj[j] = g2[cc]; bbj[j] = b2[cc]; }
        if constexpr (ACT == 3) { csj[j] = colsum[cc]; }
    }
#pragma unroll
    for (int i = 0; i < 4; ++i)
#pragma unroll
        for (int r = 0; r < 4; ++r) {
            int grow = bm + wm + 16 * i + rq + r;
            if (grow >= M) continue;
            float rsv = 0.f, rmu = 0.f;
            if constexpr (ACT == 3) { rsv = rsig[grow]; rmu = rsv * mu[grow]; }
#pragma unroll
            for (int j = 0; j < 4; ++j) {
                int cc = bn + wn + 16 * j + mrow;
                float v;
                if constexpr (ACT == 3) v = fmaf(rsv, acc[i][j][r], fmaf(-rmu, csj[j], bsj[j]));
                else v = acc[i][j][r] + bsj[j];
                if constexpr (ACT == 1) v = leaky(v * inv_s * gj[j] + bbj[j], 0.1f);
                else if constexpr (ACT == 2) v = leaky(v, 0.1f);
                if constexpr (OUT == 0)      ((float*)Cv)[(size_t)grow * N + cc] = v;
                else if constexpr (OUT == 1) ((__half*)Cv)[(size_t)grow * N + cc] = __float2half(v);
                else {
                    if (bn < 256) C8[(size_t)grow * 256 + cc] = f2fp8(v);
                    else          C16[(size_t)grow * 256 + (cc - 256)] = __float2half(v);
                }
            }
        }
}

// ------- fused exit-2 + output head: out = (leaky(y1 @ h2 + b2)) @ h3 + b3 -------
// N=128 fixed; each block covers 128 rows x all 128 cols -> final dot completes in-block.
__global__ __launch_bounds__(256) void gemm_out_k(
    const __half* __restrict__ A, const __half* __restrict__ Bt,
    const float* __restrict__ bias, const float* __restrict__ w3,
    const float* __restrict__ b3, float* __restrict__ out, int M, int K)
{
    __shared__ _Float16 As[128 * 64];
    __shared__ _Float16 Bs[128 * 64];
    __shared__ float red[128][2];
    const int tid = threadIdx.x, lane = tid & 63, wave = tid >> 6;
    const int bm = blockIdx.x * 128;
    const int wm = (wave & 1) * 64, wn = (wave >> 1) * 64;
    const int mrow = lane & 15;
    const int sg = lane >> 3;
    const int sc = (lane & 7) ^ sg;

    f32x4 acc[4][4];
#pragma unroll
    for (int i = 0; i < 4; ++i)
#pragma unroll
        for (int j = 0; j < 4; ++j) acc[i][j] = (f32x4){0.f, 0.f, 0.f, 0.f};

    for (int k0 = 0; k0 < K; k0 += 64) {
#pragma unroll
        for (int t = 0; t < 4; ++t) {
            int R = 32 * wave + 8 * t;
            int ar = bm + R + sg; if (ar >= M) ar = M - 1;
            GLD16(A + (size_t)ar * K + k0 + sc * 8, &As[R * 64]);
        }
#pragma unroll
        for (int t = 0; t < 4; ++t) {
            int R = 32 * wave + 8 * t;
            GLD16(Bt + (size_t)(R + sg) * K + k0 + sc * 8, &Bs[R * 64]);
        }
        __syncthreads();
#pragma unroll
        for (int s2 = 0; s2 < 2; ++s2) {
            const int c = s2 * 4 + (lane >> 4);
            f16x8 af[4], bf[4];
#pragma unroll
            for (int i = 0; i < 4; ++i) {
                int r = wm + 16 * i + mrow;
                af[i] = *(const f16x8*)&As[r * 64 + ((c ^ (r & 7)) * 8)];
            }
#pragma unroll
            for (int j = 0; j < 4; ++j) {
                int r = wn + 16 * j + mrow;
                bf[j] = *(const f16x8*)&Bs[r * 64 + ((c ^ (r & 7)) * 8)];
            }
#pragma unroll
            for (int i = 0; i < 4; ++i)
#pragma unroll
                for (int j = 0; j < 4; ++j)
                    acc[i][j] = __builtin_amdgcn_mfma_f32_16x16x32_f16(af[i], bf[j], acc[i][j], 0, 0, 0);
        }
        __syncthreads();
    }

    const int rq = (lane >> 4) * 4;
    float bsj[4], w3j[4];
#pragma unroll
    for (int j = 0; j < 4; ++j) {
        int cc = wn + 16 * j + mrow;
        bsj[j] = bias[cc];
        w3j[j] = w3[cc];
    }
#pragma unroll
    for (int i = 0; i < 4; ++i)
#pragma unroll
        for (int r = 0; r < 4; ++r) {
            int row = wm + 16 * i + rq + r;   // 0..127 within tile
            float pm = 0.f;
#pragma unroll
            for (int j = 0; j < 4; ++j) {
                float v = leaky(acc[i][j][r] + bsj[j], 0.1f);
                pm = fmaf(v, w3j[j], pm);
            }
            pm += __shfl_xor(pm, 1);
            pm += __shfl_xor(pm, 2);
            pm += __shfl_xor(pm, 4);
            pm += __shfl_xor(pm, 8);
            if (mrow == 0) red[row][wave >> 1] = pm;
        }
    __syncthreads();
    if (tid < 128) {
        int g = bm + tid;
        if (g < M) out[g] = red[tid][0] + red[tid][1] + b3[0];
    }
}

// ------- entry LN stats: mu/rsig of h16; hacc init = h16 -------
__global__ __launch_bounds__(256) void ln_stats_k(const __half* __restrict__ h16,
                                                  __half* __restrict__ hacc,
                                                  float* __restrict__ mu,
                                                  float* __restrict__ rsig, int N)
{
    int wv = blockIdx.x * 4 + (threadIdx.x >> 6);
    if (wv >= N) return;
    int lane = threadIdx.x & 63;
    size_t off = (size_t)wv * 256 + lane * 4;
    uint2 u = *(const uint2*)((const unsigned short*)h16 + off);
    f16x2 p0 = asf2(u.x), p1 = asf2(u.y);
    float v0 = (float)p0[0], v1 = (float)p0[1], v2 = (float)p1[0], v3 = (float)p1[1];
    float s = v0 + v1 + v2 + v3;
#pragma unroll
    for (int o = 1; o < 64; o <<= 1) s += __shfl_xor(s, o);
    float m = s * (1.f / 256.f);
    float d0 = v0 - m, d1 = v1 - m, d2 = v2 - m, d3 = v3 - m;
    float q = d0 * d0 + d1 * d1 + d2 * d2 + d3 * d3;
#pragma unroll
    for (int o = 1; o < 64; o <<= 1) q += __shfl_xor(q, o);
    float rs = rsqrtf(q * (1.f / 256.f) + EPSF);
    *(uint2*)((unsigned short*)hacc + off) = u;
    if (lane == 0) { mu[wv] = m; rsig[wv] = rs; }
}

// ---------------- CSR build ----------------
__global__ __launch_bounds__(256) void hist_k(const int* __restrict__ ei, int E, int N,
                                              int* __restrict__ counts)
{
    int e = blockIdx.x * 256 + threadIdx.x;
    int Etot = E + N;
    if (e >= Etot) return;
    int d = (e < E) ? ei[E + e] : (e - E);
    atomicAdd(&counts[d], 1);
}

// ---- 3-phase grid scan ----
__global__ __launch_bounds__(256) void scanA_k(const int* __restrict__ counts,
                                               int* __restrict__ bsum, int N)
{
    int i = blockIdx.x * 256 + threadIdx.x;
    int v = (i < N) ? counts[i] : 0;
    int s = v;
#pragma unroll
    for (int o = 1; o < 64; o <<= 1) s += __shfl_xor(s, o);
    __shared__ int ws[4];
    if ((threadIdx.x & 63) == 0) ws[threadIdx.x >> 6] = s;
    __syncthreads();
    if (threadIdx.x == 0) bsum[blockIdx.x] = ws[0] + ws[1] + ws[2] + ws[3];
}

__global__ __launch_bounds__(256) void scanB_k(const int* __restrict__ bsum,
                                               int* __restrict__ bpre, int nb)
{
    int t = threadIdx.x;
    int v = (t < nb) ? bsum[t] : 0;
    int lane = t & 63, w = t >> 6;
    int incl = v;
#pragma unroll
    for (int o = 1; o < 64; o <<= 1) { int u = __shfl_up(incl, o); if (lane >= o) incl += u; }
    __shared__ int ws[4];
    if (lane == 63) ws[w] = incl;
    __syncthreads();
    if (t == 0) { int run = 0; for (int k = 0; k < 4; ++k) { int x = ws[k]; ws[k] = run; run += x; } }
    __syncthreads();
    if (t < nb) bpre[t] = ws[w] + incl - v;
}

__global__ __launch_bounds__(256) void scanC_k(int* __restrict__ counts,
                                               const int* __restrict__ bpre,
                                               int* __restrict__ offsets, int N, int Etot)
{
    int i = blockIdx.x * 256 + threadIdx.x;
    int v = (i < N) ? counts[i] : 0;
    int lane = threadIdx.x & 63, w = threadIdx.x >> 6;
    int incl = v;
#pragma unroll
    for (int o = 1; o < 64; o <<= 1) { int u = __shfl_up(incl, o); if (lane >= o) incl += u; }
    __shared__ int ws[4];
    if (lane == 63) ws[w] = incl;
    __syncthreads();
    if (threadIdx.x == 0) { int run = 0; for (int k = 0; k < 4; ++k) { int x = ws[k]; ws[k] = run; run += x; } }
    __syncthreads();
    int ex = bpre[blockIdx.x] + ws[w] + incl - v;
    if (i < N) { offsets[i] = ex; counts[i] = ex; }   // counts becomes the scatter cursor
    if (i == 0) offsets[N] = Etot;
}

__global__ __launch_bounds__(256) void scatter_k(const int* __restrict__ ei, int E, int N,
                                                 int* __restrict__ cursor, int* __restrict__ eidx)
{
    int e = blockIdx.x * 256 + threadIdx.x;
    int Etot = E + N;
    if (e >= Etot) return;
    int s, d;
    if (e < E) { s = ei[e]; d = ei[E + e]; }
    else       { s = e - E; d = s; }
    int pos = atomicAdd(&cursor[d], 1);
    eidx[pos] = s;
}

// ------- Edge aggregation: wave/node, 4 slots x 16 lanes x 16 ch; fp8 xl gather -------
__global__ __launch_bounds__(256) void edge_k(
    const unsigned char* __restrict__ xl8, const __half* __restrict__ xr16,
    const __half* __restrict__ atth, const float* __restrict__ convb,
    const int* __restrict__ offsets, const int* __restrict__ eidx,
    __half* __restrict__ h16, __half* __restrict__ hacc,
    float* __restrict__ mu, float* __restrict__ rsig,
    const float* __restrict__ wsm, const float* __restrict__ scales,
    int layer, int N)
{
    int wv = blockIdx.x * 4 + (threadIdx.x >> 6);
    if (wv >= N) return;
    const int lane = threadIdx.x & 63;
    const int slot = lane >> 4, sl = lane & 15;
    const int c0 = sl * 16;               // this lane's 16-channel segment (head = sl>>1)

    f16x2 atv[8], xrv[8];
    {
        const unsigned short* ap = (const unsigned short*)atth + c0;
        const unsigned short* xp = (const unsigned short*)xr16 + (size_t)wv * 256 + c0;
        uint4 a0 = *(const uint4*)ap, a1 = *(const uint4*)(ap + 8);
        uint4 x0 = *(const uint4*)xp, x1 = *(const uint4*)(xp + 8);
        atv[0]=asf2(a0.x); atv[1]=asf2(a0.y); atv[2]=asf2(a0.z); atv[3]=asf2(a0.w);
        atv[4]=asf2(a1.x); atv[5]=asf2(a1.y); atv[6]=asf2(a1.z); atv[7]=asf2(a1.w);
        xrv[0]=asf2(x0.x); xrv[1]=asf2(x0.y); xrv[2]=asf2(x0.z); xrv[3]=asf2(x0.w);
        xrv[4]=asf2(x1.x); xrv[5]=asf2(x1.y); xrv[6]=asf2(x1.z); xrv[7]=asf2(x1.w);
    }
    const int e0 = offsets[wv], e1 = offsets[wv + 1], e1m = e1 - 1;
    f16x2 a2[8];
#pragma unroll
    for (int p = 0; p < 8; ++p) a2[p] = pk2(0.f, 0.f);
    float den = 0.f;

    for (int base = e0; base < e1; base += 4) {
        int e = base + slot;
        bool v = e < e1;
        int s = eidx[v ? e : e1m];
        uint4 w = *(const uint4*)(xl8 + (size_t)s * 256 + c0);   // 16 fp8 ch
        f16x2 xv[8];
        xv[0] = __builtin_amdgcn_cvt_scalef32_pk_f16_fp8(w.x, 1.0f, false);
        xv[1] = __builtin_amdgcn_cvt_scalef32_pk_f16_fp8(w.x, 1.0f, true);
        xv[2] = __builtin_amdgcn_cvt_scalef32_pk_f16_fp8(w.y, 1.0f, false);
        xv[3] = __builtin_amdgcn_cvt_scalef32_pk_f16_fp8(w.y, 1.0f, true);
        xv[4] = __builtin_amdgcn_cvt_scalef32_pk_f16_fp8(w.z, 1.0f, false);
        xv[5] = __builtin_amdgcn_cvt_scalef32_pk_f16_fp8(w.z, 1.0f, true);
        xv[6] = __builtin_amdgcn_cvt_scalef32_pk_f16_fp8(w.w, 1.0f, false);
        xv[7] = __builtin_amdgcn_cvt_scalef32_pk_f16_fp8(w.w, 1.0f, true);
        float pm = 0.f;
#pragma unroll
        for (int p = 0; p < 8; ++p) {
            f16x2 t = lrelu2_02(xv[p] + xrv[p]);
            pm = __builtin_amdgcn_fdot2(t, atv[p], pm, false);
        }
        pm += __shfl_xor(pm, 1);             // head = 2 lanes (32 ch)
        float exf = v ? __expf(pm) : 0.f;
        den += exf;
        _Float16 eh = (_Float16)exf;
        f16x2 e2; e2[0] = eh; e2[1] = eh;
#pragma unroll
        for (int p = 0; p < 8; ++p) a2[p] += xv[p] * e2;
    }

    // combine across the 4 slots (lane bits 4,5)
    den += __shfl_xor(den, 16); den += __shfl_xor(den, 32);
#pragma unroll
    for (int p = 0; p < 8; ++p) {
        a2[p] += asf2((unsigned int)__shfl_xor((int)asu2(a2[p]), 16));
        a2[p] += asf2((unsigned int)__shfl_xor((int)asu2(a2[p]), 32));
    }

    // all-lane epilogue: lane handles 4 channels cc = c0 + 4*slot (a2[2*slot], a2[2*slot+1])
    const int p0 = 2 * slot;
    const float inv = 1.f / den;
    const float sc = scales[layer], Sl = wsm[8 + layer];
    const int cc = c0 + 4 * slot;
    const size_t rb = (size_t)wv * 256 + cc;
    float4 cb = *(const float4*)(convb + cc);
    uint2 hu = *(const uint2*)((const unsigned short*)h16 + rb);
    f16x2 h0 = asf2(hu.x), h1 = asf2(hu.y);
    float d00 = sc * leaky(fmaf((float)a2[p0][0],     inv, cb.x), 0.1f);
    float d01 = sc * leaky(fmaf((float)a2[p0][1],     inv, cb.y), 0.1f);
    float d10 = sc * leaky(fmaf((float)a2[p0 + 1][0], inv, cb.z), 0.1f);
    float d11 = sc * leaky(fmaf((float)a2[p0 + 1][1], inv, cb.w), 0.1f);
    float hn0 = (float)h0[0] + d00, hn1 = (float)h0[1] + d01;
    float hn2 = (float)h1[0] + d10, hn3 = (float)h1[1] + d11;

    // hacc += S_l * d   (hsum = h_entry + sum_l S_l d_l; softmax weights sum to 1)
    {
        uint2 au = *(const uint2*)((const unsigned short*)hacc + rb);
        f16x2 A0 = asf2(au.x), A1 = asf2(au.y);
        uint2 ao;
        ao.x = asu2(pk2(fmaf(Sl, d00, (float)A0[0]), fmaf(Sl, d01, (float)A0[1])));
        ao.y = asu2(pk2(fmaf(Sl, d10, (float)A1[0]), fmaf(Sl, d11, (float)A1[1])));
        *(uint2*)((unsigned short*)hacc + rb) = ao;
    }

    if (layer != LL - 1) {
        uint2 ho;
        ho.x = asu2(pk2(hn0, hn1));
        ho.y = asu2(pk2(hn2, hn3));
        *(uint2*)((unsigned short*)h16 + rb) = ho;
        // LN stats across the full wave (each lane holds 4 distinct channels)
        float s1 = hn0 + hn1 + hn2 + hn3;
#pragma unroll
        for (int o = 1; o < 64; o <<= 1) s1 += __shfl_xor(s1, o);
        float m = s1 * (1.f / 256.f);
        float dd0 = hn0 - m, dd1 = hn1 - m, dd2 = hn2 - m, dd3 = hn3 - m;
        float qv = dd0 * dd0 + dd1 * dd1 + dd2 * dd2 + dd3 * dd3;
#pragma unroll
        for (int o = 1; o < 64; o <<= 1) qv += __shfl_xor(qv, o);
        float rs = rsqrtf(qv * (1.f / 256.f) + EPSF);
        if (lane == 0) { mu[wv] = m; rsig[wv] = rs; }
    }
}

extern "C" void kernel_launch(void* const* d_in, const int* in_sizes, int n_in,
                              void* d_out, int out_size, void* d_ws, size_t ws_size,
                              hipStream_t stream)
{
    const int N = NN, E = EE, Etot = EE + NN;
    const float* x      = (const float*)d_in[0];
    const int*   ei     = (const int*)  d_in[1];
    const float* win_w  = (const float*)d_in[2];
    const float* win_b  = (const float*)d_in[3];
    const float* bn1_g  = (const float*)d_in[4];
    const float* bn1_b  = (const float*)d_in[5];
    const float* ln_g   = (const float*)d_in[6];
    const float* ln_b   = (const float*)d_in[7];
    const float* Wl     = (const float*)d_in[8];
    const float* bl     = (const float*)d_in[9];
    const float* Wr     = (const float*)d_in[10];
    const float* br     = (const float*)d_in[11];
    const float* att    = (const float*)d_in[12];
    const float* conv_b = (const float*)d_in[13];
    const float* scales = (const float*)d_in[14];
    const float* sw     = (const float*)d_in[15];
    const float* h1_w   = (const float*)d_in[16];
    const float* h1_b   = (const float*)d_in[17];
    const float* bn2_g  = (const float*)d_in[18];
    const float* bn2_b  = (const float*)d_in[19];
    const float* h2_w   = (const float*)d_in[20];
    const float* h2_b   = (const float*)d_in[21];
    const float* h3_w   = (const float*)d_in[22];
    const float* h3_b   = (const float*)d_in[23];

    char* p = (char*)d_ws;
    auto take = [&](size_t b) -> char* {
        char* q = p; p += (b + 255) & ~(size_t)255; return q;
    };
    __half* h16     = (__half*)take((size_t)N * 256 * 2);
    __half* hacc    = (__half*)take((size_t)N * 256 * 2);
    float*  mu      = (float*)take((size_t)N * 4);
    float*  rsig    = (float*)take((size_t)N * 4);
    unsigned char* xl8 = (unsigned char*)take((size_t)N * 256);
    __half* xr16    = (__half*)take((size_t)N * 256 * 2);
    __half* xh      = (__half*)take((size_t)N * 128 * 2);
    float* wsm      = (float*)take(256);
    int*   offsets  = (int*)take((size_t)(N + 1) * 4);
    int*   cursor   = (int*)take((size_t)N * 4);
    int*   eidx     = (int*)take((size_t)Etot * 4);
    int*   bsum     = (int*)take(256 * 4);
    int*   bpre     = (int*)take(256 * 4);
    __half* winT    = (__half*)take((size_t)256 * 128 * 2);
    __half* WlrT    = (__half*)take((size_t)LL * 512 * 256 * 2);
    __half* h1T     = (__half*)take((size_t)256 * 256 * 2);
    __half* h2T     = (__half*)take((size_t)128 * 256 * 2);
    __half* att_h   = (__half*)take((size_t)LL * 256 * 2);
    float* biasLR   = (float*)take((size_t)LL * 512 * 4);
    float* colsumLR = (float*)take((size_t)LL * 512 * 4);
    __half* y1b = xr16;   // xr16 dead after layer-5 edge_k

    const int EB = (Etot + 255) / 256;
    const int NB = (N + 3) / 4;
    const int SB = (N + 255) / 256;    // 196 scan blocks
    const int MB = (N + 127) / 128;    // 391 gemm row blocks
    const int CVB = (N * 128 + 255) / 256;   // x->fp16 blocks (25000)

    // CSR build (cursor doubles as counts, then as scatter cursor after scanC)
    hipMemsetAsync(cursor, 0, (size_t)N * 4, stream);
    hist_k<<<EB, 256, 0, stream>>>(ei, E, N, cursor);
    scanA_k<<<SB, 256, 0, stream>>>(cursor, bsum, N);
    scanB_k<<<1, 256, 0, stream>>>(bsum, bpre, SB);
    scanC_k<<<SB, 256, 0, stream>>>(cursor, bpre, offsets, N, Etot);
    scatter_k<<<EB, 256, 0, stream>>>(ei, E, N, cursor, eidx);

    // fused prep: transposes(+gamma), biasfold(+beta), colsum, att cvt, softmax, x->fp16
    prep_k<<<243 + CVB, 256, 0, stream>>>(win_w, Wl, Wr, h1_w, h2_w, ln_g, ln_b, bl, br,
                                          att, sw, x, xh,
                                          winT, WlrT, h1T, h2T, att_h, biasLR, colsumLR, wsm);

    dim3 g2d(MB, 2);   // 391 x 2
    dim3 g4d(MB, 4);   // 391 x 4

    // entry: h16 = leaky(bn1(x @ win_w + win_b), 0.1) fp16; stats + hacc init
    gemm_h_k<1, 1><<<g2d, 256, 0, stream>>>(xh, winT, win_b, bn1_g, bn1_b,
                                            nullptr, nullptr, nullptr,
                                            h16, nullptr, nullptr, N, 128, 256);
    ln_stats_k<<<NB, 256, 0, stream>>>(h16, hacc, mu, rsig, N);

    for (int l = 0; l < LL; ++l) {
        // xl8/xr16 = LN(h16) @ WlrT + biasLR, LN applied in epilogue via colsum identity
        gemm_h_k<3, 2><<<g4d, 256, 0, stream>>>(h16, WlrT + (size_t)l * 131072,
                                                biasLR + l * 512, nullptr, nullptr,
                                                mu, rsig, colsumLR + l * 512,
                                                nullptr, xl8, xr16, N, 256, 512);
        edge_k<<<NB, 256, 0, stream>>>(xl8, xr16, att_h + l * 256, conv_b + l * 256,
                                       offsets, eidx, h16, hacc, mu, rsig,
                                       wsm, scales, l, N);
    }

    // exit MLP on hacc (= softmax-weighted layer sum, fp16)
    gemm_h_k<1, 1><<<g2d, 256, 0, stream>>>(hacc, h1T, h1_b, bn2_g, bn2_b,
                                            nullptr, nullptr, nullptr,
                                            y1b, nullptr, nullptr, N, 256, 256);
    // fused: out = leaky(y1 @ h2_w + h2_b) @ h3_w + h3_b
    gemm_out_k<<<dim3(MB, 1), 256, 0, stream>>>(y1b, h2T, h2_b, h3_w, h3_b,
                                                (float*)d_out, N, 256);
}